// Round 5
// baseline (66803.076 us; speedup 1.0000x reference)
//
#include <hip/hip_runtime.h>
#include <hip/hip_bf16.h>
#include <math.h>

#define BATCH 1024
#define RKSTEPS 16
#define NBLK 256

typedef unsigned short us;
typedef __bf16 bf16x8 __attribute__((ext_vector_type(8)));
typedef float f32x16 __attribute__((ext_vector_type(16)));

enum { EM_PLAIN_F32=0, EM_TANH=1, EM_TANH_RES=2, EM_TANH_OUT=6 };

__device__ __forceinline__ us f2bf(float f){
    unsigned int u = __float_as_uint(f);
    u += 0x7fffu + ((u >> 16) & 1u);
    return (us)(u >> 16);
}
__device__ __forceinline__ float bf2f(us h){
    return __uint_as_float(((unsigned int)h) << 16);
}
__device__ __forceinline__ void split_store(float v, us* ph, us* pl, size_t idx){
    us hh = f2bf(v); ph[idx] = hh; pl[idx] = f2bf(v - bf2f(hh));
}

// ---- preprocessing: split x + zero barrier counter ----
__global__ __launch_bounds__(256) void xsplit(const float* __restrict__ src,
                                              us* __restrict__ h, us* __restrict__ l,
                                              int n, unsigned* ctr){
    if (blockIdx.x == 0 && threadIdx.x == 0) *ctr = 0u;
    int i = blockIdx.x * 256 + threadIdx.x;
    if (i < n){
        float v = src[i];
        us hh = f2bf(v);
        h[i] = hh;
        l[i] = f2bf(v - bf2f(hh));
    }
}

// ---- preprocessing: all weight transpose+splits in ONE kernel ----
struct WsDesc { const float* src; us* h; us* l; int K; int N; int tile0; };
struct WsTable { WsDesc d[22]; };

__global__ __launch_bounds__(256) void wsplit_all(WsTable T){
    __shared__ float tile[32][33];
    const int t = blockIdx.x;
    int mi = 0;
    #pragma unroll 1
    for (int i = 1; i < 22; ++i) if (t >= T.d[i].tile0) mi = i;  // sentinels: tile0=INT_MAX
    const WsDesc dd = T.d[mi];
    const int local = t - dd.tile0;
    const int tilesx = dd.K >> 5;
    const int k0 = (local % tilesx) * 32;
    const int n0 = (local / tilesx) * 32;
    const int tt = threadIdx.x;
    const int r = tt >> 3;
    const int c4 = (tt & 7) * 4;
    const float4 v = *(const float4*)&dd.src[(size_t)(k0 + r) * dd.N + n0 + c4];
    tile[r][c4+0] = v.x; tile[r][c4+1] = v.y; tile[r][c4+2] = v.z; tile[r][c4+3] = v.w;
    __syncthreads();
    ushort4 hh, ll;
    #pragma unroll
    for (int j = 0; j < 4; ++j){
        float x = tile[c4 + j][r];
        us hb = f2bf(x);
        ((us*)&hh)[j] = hb;
        ((us*)&ll)[j] = f2bf(x - bf2f(hb));
    }
    *(ushort4*)&dd.h[(size_t)(n0 + r) * dd.K + k0 + c4] = hh;
    *(ushort4*)&dd.l[(size_t)(n0 + r) * dd.K + k0 + c4] = ll;
}

// ---- small GEMMs for input/output MLP (validated round-2 kernel) ----
__global__ __launch_bounds__(128) void gemm3p(
    const us* __restrict__ Ah, const us* __restrict__ Al,
    const us* __restrict__ Bh, const us* __restrict__ Bl,
    const float* __restrict__ bias,
    int M, int N, int K, int mode,
    us* __restrict__ outh, us* __restrict__ outl,
    float* outf, const float* res32)
{
    __shared__ us Ash[32][72];
    __shared__ us Asl[32][72];
    __shared__ us Bsh[64][72];
    __shared__ us Bsl[64][72];

    const int tid  = threadIdx.x;
    const int lane = tid & 63;
    const int w    = tid >> 6;
    const int m0   = blockIdx.y * 32;
    const int n0   = blockIdx.x * 64;

    f32x16 accA, accB;
    #pragma unroll
    for (int i = 0; i < 16; ++i){ accA[i] = 0.f; accB[i] = 0.f; }

    uint4 rAh[2], rAl[2], rBh[4], rBl[4];
    auto stage_load = [&](int k0){
        #pragma unroll
        for (int p = 0; p < 2; ++p){
            int id = p * 128 + tid; int r = id >> 3; int c = (id & 7) * 8;
            size_t off = (size_t)(m0 + r) * K + k0 + c;
            rAh[p] = *(const uint4*)&Ah[off];
            rAl[p] = *(const uint4*)&Al[off];
        }
        #pragma unroll
        for (int p = 0; p < 4; ++p){
            int id = p * 128 + tid; int r = id >> 3; int c = (id & 7) * 8;
            size_t off = (size_t)(n0 + r) * K + k0 + c;
            rBh[p] = *(const uint4*)&Bh[off];
            rBl[p] = *(const uint4*)&Bl[off];
        }
    };
    auto stage_write = [&](){
        #pragma unroll
        for (int p = 0; p < 2; ++p){
            int id = p * 128 + tid; int r = id >> 3; int c = (id & 7) * 8;
            *(uint4*)&Ash[r][c] = rAh[p];
            *(uint4*)&Asl[r][c] = rAl[p];
        }
        #pragma unroll
        for (int p = 0; p < 4; ++p){
            int id = p * 128 + tid; int r = id >> 3; int c = (id & 7) * 8;
            *(uint4*)&Bsh[r][c] = rBh[p];
            *(uint4*)&Bsl[r][c] = rBl[p];
        }
    };

    stage_load(0);
    stage_write();
    __syncthreads();

    const int arow = lane & 31;
    const int brow = w * 32 + (lane & 31);
    const int g8   = (lane >> 5) * 8;

    for (int k0 = 0; k0 < K; k0 += 64){
        const bool more = (k0 + 64) < K;
        if (more) stage_load(k0 + 64);
        #pragma unroll
        for (int kc = 0; kc < 4; ++kc){
            const int koff = kc * 16 + g8;
            bf16x8 a_h = *(const bf16x8*)&Ash[arow][koff];
            bf16x8 a_l = *(const bf16x8*)&Asl[arow][koff];
            bf16x8 b_h = *(const bf16x8*)&Bsh[brow][koff];
            bf16x8 b_l = *(const bf16x8*)&Bsl[brow][koff];
            accA = __builtin_amdgcn_mfma_f32_32x32x16_bf16(a_h, b_h, accA, 0, 0, 0);
            accB = __builtin_amdgcn_mfma_f32_32x32x16_bf16(a_h, b_l, accB, 0, 0, 0);
            accB = __builtin_amdgcn_mfma_f32_32x32x16_bf16(a_l, b_h, accB, 0, 0, 0);
        }
        if (more){
            __syncthreads();
            stage_write();
            __syncthreads();
        }
    }

    const int col = n0 + w * 32 + (lane & 31);
    const float bc = bias[col];
    const int g4 = (lane >> 5) * 4;
    #pragma unroll
    for (int r = 0; r < 16; ++r){
        const int row = m0 + (r & 3) + 8 * (r >> 2) + g4;
        const size_t idx = (size_t)row * N + col;
        float z = accA[r] + accB[r] + bc;
        if (mode == EM_PLAIN_F32){
            outf[idx] = z;
        } else if (mode == EM_TANH){
            float t = tanhf(z);
            split_store(t, outh, outl, idx);
        } else if (mode == EM_TANH_RES){
            float t = tanhf(z) + res32[idx];
            outf[idx] = t;
            split_store(t, outh, outl, idx);
        } else { // EM_TANH_OUT
            outf[idx] = tanhf(z);
        }
    }
}

// ---- device-scope grid barrier (monotonic counter, timeout-protected) ----
__device__ __forceinline__ void grid_bar(unsigned* ctr, unsigned target){
    __syncthreads();
    if (threadIdx.x == 0){
        __threadfence();
        __hip_atomic_fetch_add(ctr, 1u, __ATOMIC_ACQ_REL, __HIP_MEMORY_SCOPE_AGENT);
        long long t0 = (long long)__builtin_amdgcn_s_memrealtime();
        while (__hip_atomic_load(ctr, __ATOMIC_ACQUIRE, __HIP_MEMORY_SCOPE_AGENT) < target){
            __builtin_amdgcn_s_sleep(1);
            if ((long long)__builtin_amdgcn_s_memrealtime() - t0 > 200000000LL) break; // safety: no hang
        }
        __threadfence();
    }
    __syncthreads();
}

// ---- the fused ODE mega-kernel ----
// 256 blocks (1/CU), 256 threads. Each block owns rows m0..m0+63 and a fixed
// column tile of every GEMM stage. XCD mapping: mrow tied to XCD so activation
// row-panels stay in the producing XCD's L2; weights stream from L3.
__global__ __launch_bounds__(256, 1) void fused_ode(
    const us* __restrict__ W1t_h, const us* __restrict__ W1t_l, const float* __restrict__ B1,
    const us* __restrict__ W2t_h, const us* __restrict__ W2t_l, const float* __restrict__ B2,
    const us* __restrict__ W3t_h, const us* __restrict__ W3t_l, const float* __restrict__ B3,
    us* __restrict__ yh,  us* __restrict__ yl,
    us* __restrict__ yth, us* __restrict__ ytl,
    us* __restrict__ a1h, us* __restrict__ a1l,
    us* __restrict__ a2h, us* __restrict__ a2l,
    float* __restrict__ y32, float* __restrict__ kacc,
    unsigned* ctr)
{
    __shared__ us smem[18432];   // 36,864 B: A(64x72 hi/lo) + B(64x72 hi/lo)
    us* Ash = smem;
    us* Asl = smem + 4608;
    us* Bsh = smem + 9216;
    us* Bsl = smem + 13824;

    const int tid  = threadIdx.x;
    const int lane = tid & 63;
    const int w    = tid >> 6;
    const int bid  = blockIdx.x;
    // bid bits: [2:0]=xcd, [3]=m-sub, [7:4]=ncol
    const int mrow = (bid & 7) * 2 + ((bid >> 3) & 1);   // 0..15
    const int ncol = bid >> 4;                            // 0..15
    const int m0  = mrow * 64;
    const int n0  = ncol * 64;
    const int n0c = ncol * 32;
    const float hs = 1.0f / (float)RKSTEPS;
    unsigned epoch = 0;

    // 64x64-tile 3-pass GEMM: A [64][sA] via Ahp/Alp (row m0 applied),
    // B [64][K] via Bhp/Blp (row n0 applied). acc in c0..c2.
    auto gemm64 = [&](const us* Ahp, const us* Alp, int sA,
                      const us* Bhp, const us* Blp, int K,
                      f32x16& c0, f32x16& c1, f32x16& c2){
        uint4 rAh[2], rAl[2], rBh[2], rBl[2];
        auto ld = [&](int k0){
            #pragma unroll
            for (int p = 0; p < 2; ++p){
                int id = p * 256 + tid; int rr = id >> 3; int cc = (id & 7) * 8;
                rAh[p] = *(const uint4*)&Ahp[(size_t)rr * sA + k0 + cc];
                rAl[p] = *(const uint4*)&Alp[(size_t)rr * sA + k0 + cc];
                rBh[p] = *(const uint4*)&Bhp[(size_t)rr * K + k0 + cc];
                rBl[p] = *(const uint4*)&Blp[(size_t)rr * K + k0 + cc];
            }
        };
        auto wr = [&](){
            #pragma unroll
            for (int p = 0; p < 2; ++p){
                int id = p * 256 + tid; int rr = id >> 3; int cc = (id & 7) * 8;
                *(uint4*)&Ash[rr * 72 + cc] = rAh[p];
                *(uint4*)&Asl[rr * 72 + cc] = rAl[p];
                *(uint4*)&Bsh[rr * 72 + cc] = rBh[p];
                *(uint4*)&Bsl[rr * 72 + cc] = rBl[p];
            }
        };
        const int aoff = ((w >> 1) * 32 + (lane & 31)) * 72;
        const int boff = ((w & 1)  * 32 + (lane & 31)) * 72;
        const int g8   = (lane >> 5) * 8;
        ld(0);
        for (int k0 = 0; k0 < K; k0 += 64){
            wr(); __syncthreads();
            if (k0 + 64 < K) ld(k0 + 64);
            #pragma unroll
            for (int kc = 0; kc < 4; ++kc){
                int ko = kc * 16 + g8;
                bf16x8 ah = *(const bf16x8*)&Ash[aoff + ko];
                bf16x8 al = *(const bf16x8*)&Asl[aoff + ko];
                bf16x8 bh = *(const bf16x8*)&Bsh[boff + ko];
                bf16x8 bl = *(const bf16x8*)&Bsl[boff + ko];
                c0 = __builtin_amdgcn_mfma_f32_32x32x16_bf16(ah, bh, c0, 0, 0, 0);
                c1 = __builtin_amdgcn_mfma_f32_32x32x16_bf16(ah, bl, c1, 0, 0, 0);
                c2 = __builtin_amdgcn_mfma_f32_32x32x16_bf16(al, bh, c2, 0, 0, 0);
            }
            __syncthreads();
        }
    };

    // 64x32-tile GEMM (stage C): B has 32 rows; waves 0,1 do MFMA (full K),
    // all 4 waves help stage. K=1024, sA=1024 fixed.
    auto gemmC = [&](const us* Ahp, const us* Alp,
                     const us* Bhp, const us* Blp,
                     f32x16& c0, f32x16& c1, f32x16& c2){
        uint4 rAh[2], rAl[2], rBh, rBl;
        auto ld = [&](int k0){
            #pragma unroll
            for (int p = 0; p < 2; ++p){
                int id = p * 256 + tid; int rr = id >> 3; int cc = (id & 7) * 8;
                rAh[p] = *(const uint4*)&Ahp[(size_t)rr * 1024 + k0 + cc];
                rAl[p] = *(const uint4*)&Alp[(size_t)rr * 1024 + k0 + cc];
            }
            { int rr = tid >> 3; int cc = (tid & 7) * 8;
              rBh = *(const uint4*)&Bhp[(size_t)rr * 1024 + k0 + cc];
              rBl = *(const uint4*)&Blp[(size_t)rr * 1024 + k0 + cc]; }
        };
        auto wr = [&](){
            #pragma unroll
            for (int p = 0; p < 2; ++p){
                int id = p * 256 + tid; int rr = id >> 3; int cc = (id & 7) * 8;
                *(uint4*)&Ash[rr * 72 + cc] = rAh[p];
                *(uint4*)&Asl[rr * 72 + cc] = rAl[p];
            }
            { int rr = tid >> 3; int cc = (tid & 7) * 8;
              *(uint4*)&Bsh[rr * 72 + cc] = rBh;
              *(uint4*)&Bsl[rr * 72 + cc] = rBl; }
        };
        const int aoff = ((w & 1) * 32 + (lane & 31)) * 72;
        const int boff = (lane & 31) * 72;
        const int g8   = (lane >> 5) * 8;
        ld(0);
        for (int k0 = 0; k0 < 1024; k0 += 64){
            wr(); __syncthreads();
            if (k0 + 64 < 1024) ld(k0 + 64);
            if (w < 2){
                #pragma unroll
                for (int kc = 0; kc < 4; ++kc){
                    int ko = kc * 16 + g8;
                    bf16x8 ah = *(const bf16x8*)&Ash[aoff + ko];
                    bf16x8 al = *(const bf16x8*)&Asl[aoff + ko];
                    bf16x8 bh = *(const bf16x8*)&Bsh[boff + ko];
                    bf16x8 bl = *(const bf16x8*)&Bsl[boff + ko];
                    c0 = __builtin_amdgcn_mfma_f32_32x32x16_bf16(ah, bh, c0, 0, 0, 0);
                    c1 = __builtin_amdgcn_mfma_f32_32x32x16_bf16(ah, bl, c1, 0, 0, 0);
                    c2 = __builtin_amdgcn_mfma_f32_32x32x16_bf16(al, bh, c2, 0, 0, 0);
                }
            }
            __syncthreads();
        }
    };

    #pragma unroll 1
    for (int L = 0; L < 5; ++L){
        const us* W1h = W1t_h + (size_t)L * 1024 * 512;
        const us* W1l = W1t_l + (size_t)L * 1024 * 512;
        const us* W2h = W2t_h + (size_t)L * 1024 * 1024;
        const us* W2l = W2t_l + (size_t)L * 1024 * 1024;
        const us* W3h = W3t_h + (size_t)L * 512 * 1024;
        const us* W3l = W3t_l + (size_t)L * 512 * 1024;
        const float* b1 = B1 + L * 1024;
        const float* b2 = B2 + L * 1024;
        const float* b3 = B3 + L * 512;

        #pragma unroll 1
        for (int st = 0; st < RKSTEPS; ++st){
            #pragma unroll 1
            for (int s = 0; s < 4; ++s){
                const us* inh = (s == 0) ? yh : yth;
                const us* inl = (s == 0) ? yl : ytl;

                // ---- stage A: a1 = tanh(in @ W1 + b1), tile 64x64, K=512
                {
                    f32x16 c0, c1, c2;
                    #pragma unroll
                    for (int i = 0; i < 16; ++i){ c0[i]=0.f; c1[i]=0.f; c2[i]=0.f; }
                    gemm64(inh + (size_t)m0 * 512, inl + (size_t)m0 * 512, 512,
                           W1h + (size_t)n0 * 512, W1l + (size_t)n0 * 512, 512,
                           c0, c1, c2);
                    const int col = n0 + (w & 1) * 32 + (lane & 31);
                    const float bb = b1[col];
                    const int rbase = m0 + (w >> 1) * 32 + 4 * (lane >> 5);
                    #pragma unroll
                    for (int r = 0; r < 16; ++r){
                        int row = rbase + (r & 3) + 8 * (r >> 2);
                        float z = c0[r] + c1[r] + c2[r] + bb;
                        split_store(tanhf(z), a1h, a1l, (size_t)row * 1024 + col);
                    }
                }
                ++epoch; grid_bar(ctr, epoch * NBLK);

                // ---- stage B: a2 = tanh(a1 @ W2 + b2), tile 64x64, K=1024
                {
                    f32x16 c0, c1, c2;
                    #pragma unroll
                    for (int i = 0; i < 16; ++i){ c0[i]=0.f; c1[i]=0.f; c2[i]=0.f; }
                    gemm64(a1h + (size_t)m0 * 1024, a1l + (size_t)m0 * 1024, 1024,
                           W2h + (size_t)n0 * 1024, W2l + (size_t)n0 * 1024, 1024,
                           c0, c1, c2);
                    const int col = n0 + (w & 1) * 32 + (lane & 31);
                    const float bb = b2[col];
                    const int rbase = m0 + (w >> 1) * 32 + 4 * (lane >> 5);
                    #pragma unroll
                    for (int r = 0; r < 16; ++r){
                        int row = rbase + (r & 3) + 8 * (r >> 2);
                        float z = c0[r] + c1[r] + c2[r] + bb;
                        split_store(tanhf(z), a2h, a2l, (size_t)row * 1024 + col);
                    }
                }
                ++epoch; grid_bar(ctr, epoch * NBLK);

                // ---- stage C: k = a2 @ W3 + b3, tile 64x32, RK update
                {
                    f32x16 c0, c1, c2;
                    #pragma unroll
                    for (int i = 0; i < 16; ++i){ c0[i]=0.f; c1[i]=0.f; c2[i]=0.f; }
                    gemmC(a2h + (size_t)m0 * 1024, a2l + (size_t)m0 * 1024,
                          W3h + (size_t)n0c * 1024, W3l + (size_t)n0c * 1024,
                          c0, c1, c2);
                    if (w < 2){
                        const int col = n0c + (lane & 31);
                        const float bb = b3[col];
                        const int rbase = m0 + (w & 1) * 32 + 4 * (lane >> 5);
                        #pragma unroll
                        for (int r = 0; r < 16; ++r){
                            int row = rbase + (r & 3) + 8 * (r >> 2);
                            size_t idx = (size_t)row * 512 + col;
                            float z = c0[r] + c1[r] + c2[r] + bb;
                            if (s == 0){
                                kacc[idx] = z;
                                split_store(y32[idx] + 0.5f * hs * z, yth, ytl, idx);
                            } else if (s == 3){
                                float yn = y32[idx] + (hs / 6.0f) * (kacc[idx] + z);
                                y32[idx] = yn;
                                split_store(yn, yh, yl, idx);
                            } else {
                                kacc[idx] += 2.0f * z;
                                float hc = (s == 1) ? 0.5f * hs : hs;
                                split_store(y32[idx] + hc * z, yth, ytl, idx);
                            }
                        }
                    }
                }
                ++epoch; grid_bar(ctr, epoch * NBLK);
            }
        }
    }
}

extern "C" void kernel_launch(void* const* d_in, const int* in_sizes, int n_in,
                              void* d_out, int out_size, void* d_ws, size_t ws_size,
                              hipStream_t stream)
{
    (void)in_sizes; (void)n_in; (void)out_size; (void)ws_size;
    const float* x   = (const float*)d_in[0];
    const float* Wi1 = (const float*)d_in[1];
    const float* bi1 = (const float*)d_in[2];
    const float* Wi2 = (const float*)d_in[3];
    const float* bi2 = (const float*)d_in[4];
    const float* Wr  = (const float*)d_in[5];
    const float* br  = (const float*)d_in[6];
    const float* oW1 = (const float*)d_in[7];
    const float* ob1 = (const float*)d_in[8];
    const float* oW2 = (const float*)d_in[9];
    const float* ob2 = (const float*)d_in[10];
    const float* oW3 = (const float*)d_in[11];
    const float* ob3 = (const float*)d_in[12];
    const float* Wo1 = (const float*)d_in[13];
    const float* bo1 = (const float*)d_in[14];
    const float* Wo2 = (const float*)d_in[15];
    const float* bo2 = (const float*)d_in[16];
    float* out = (float*)d_out;

    char* p = (char*)d_ws;
    auto alloc = [&](size_t bytes)->char*{ char* r = p; p += (bytes + 255) & ~(size_t)255; return r; };

    us* xh = (us*)alloc(1024*256*2);  us* xl = (us*)alloc(1024*256*2);
    us* Wi1th = (us*)alloc(512*256*2);  us* Wi1tl = (us*)alloc(512*256*2);
    us* Wi2th = (us*)alloc(512*512*2);  us* Wi2tl = (us*)alloc(512*512*2);
    us* Wrth  = (us*)alloc(512*256*2);  us* Wrtl  = (us*)alloc(512*256*2);
    us* oW1th = (us*)alloc(5ull*1024*512*2);  us* oW1tl = (us*)alloc(5ull*1024*512*2);
    us* oW2th = (us*)alloc(5ull*1024*1024*2); us* oW2tl = (us*)alloc(5ull*1024*1024*2);
    us* oW3th = (us*)alloc(5ull*512*1024*2);  us* oW3tl = (us*)alloc(5ull*512*1024*2);
    us* Wo1th = (us*)alloc(512*512*2);  us* Wo1tl = (us*)alloc(512*512*2);
    us* Wo2th = (us*)alloc(128*512*2);  us* Wo2tl = (us*)alloc(128*512*2);
    us* t1h = (us*)alloc(1024ull*512*2);  us* t1l = (us*)alloc(1024ull*512*2);   // MLP temps [1024][512]
    us* a1h = (us*)alloc(1024ull*1024*2); us* a1l = (us*)alloc(1024ull*1024*2);
    us* a2h = (us*)alloc(1024ull*1024*2); us* a2l = (us*)alloc(1024ull*1024*2);
    us* yh  = (us*)alloc(1024ull*512*2);  us* yl  = (us*)alloc(1024ull*512*2);
    us* yth = (us*)alloc(1024ull*512*2);  us* ytl = (us*)alloc(1024ull*512*2);
    float* y32  = (float*)alloc(1024ull*512*4);
    float* kacc = (float*)alloc(1024ull*512*4);   // also used as rres in input block
    unsigned* ctr = (unsigned*)alloc(256);
    float* rres = kacc;  // alias: rres consumed before kacc's first RK write

    // ---- preprocessing (2 dispatches) ----
    hipLaunchKernelGGL(xsplit, dim3(1024), dim3(256), 0, stream, x, xh, xl, 1024*256, ctr);

    WsTable T;
    for (int i = 0; i < 22; ++i){
        T.d[i].src = nullptr; T.d[i].h = nullptr; T.d[i].l = nullptr;
        T.d[i].K = 32; T.d[i].N = 32; T.d[i].tile0 = 0x7fffffff;  // sentinel: never selected
    }
    int tile_acc = 0, di = 0;
    auto addW = [&](const float* W, us* th, us* tl, int K, int N){
        T.d[di].src = W; T.d[di].h = th; T.d[di].l = tl;
        T.d[di].K = K; T.d[di].N = N; T.d[di].tile0 = tile_acc;
        tile_acc += (K/32) * (N/32); ++di;
    };
    addW(Wi1, Wi1th, Wi1tl, 256, 512);
    addW(Wi2, Wi2th, Wi2tl, 512, 512);
    addW(Wr,  Wrth,  Wrtl,  256, 512);
    for (int L = 0; L < 5; ++L){
        addW(oW1 + (size_t)L*512*1024,  oW1th + (size_t)L*1024*512,  oW1tl + (size_t)L*1024*512,  512, 1024);
        addW(oW2 + (size_t)L*1024*1024, oW2th + (size_t)L*1024*1024, oW2tl + (size_t)L*1024*1024, 1024, 1024);
        addW(oW3 + (size_t)L*1024*512,  oW3th + (size_t)L*512*1024,  oW3tl + (size_t)L*512*1024,  1024, 512);
    }
    addW(Wo1, Wo1th, Wo1tl, 512, 512);
    addW(Wo2, Wo2th, Wo2tl, 512, 128);
    hipLaunchKernelGGL(wsplit_all, dim3(tile_acc), dim3(256), 0, stream, T);

    auto G = [&](const us* ah, const us* al, const us* bh, const us* bl,
                 const float* bias, int N, int K, int mode,
                 us* oh, us* ol, float* of, const float* rs){
        dim3 grid(N/64, BATCH/32);
        hipLaunchKernelGGL(gemm3p, grid, dim3(128), 0, stream,
                           ah, al, bh, bl, bias, BATCH, N, K, mode, oh, ol, of, rs);
    };

    // ---- input block (3 dispatches) ----
    G(xh, xl, Wrth, Wrtl, br, 512, 256, EM_PLAIN_F32, nullptr, nullptr, rres, nullptr);
    G(xh, xl, Wi1th, Wi1tl, bi1, 512, 256, EM_TANH, t1h, t1l, nullptr, nullptr);
    G(t1h, t1l, Wi2th, Wi2tl, bi2, 512, 512, EM_TANH_RES, yh, yl, y32, rres);

    // ---- the entire 5-layer RK4 ODE stack (1 dispatch) ----
    hipLaunchKernelGGL(fused_ode, dim3(NBLK), dim3(256), 0, stream,
                       oW1th, oW1tl, ob1, oW2th, oW2tl, ob2, oW3th, oW3tl, ob3,
                       yh, yl, yth, ytl, a1h, a1l, a2h, a2l, y32, kacc, ctr);

    // ---- output MLP (2 dispatches) ----
    G(yh, yl, Wo1th, Wo1tl, bo1, 512, 512, EM_TANH, t1h, t1l, nullptr, nullptr);
    G(t1h, t1l, Wo2th, Wo2tl, bo2, 128, 512, EM_TANH_OUT, nullptr, nullptr, out, nullptr);
}

// Round 6
// 55805.017 us; speedup vs baseline: 1.1971x; 1.1971x over previous
//
#include <hip/hip_runtime.h>
#include <hip/hip_bf16.h>
#include <math.h>

#define BATCH 1024
#define RKSTEPS 16
#define NBLK 256

typedef unsigned short us;
typedef __bf16 bf16x8 __attribute__((ext_vector_type(8)));
typedef float f32x16 __attribute__((ext_vector_type(16)));

enum { EM_PLAIN_F32=0, EM_TANH=1, EM_TANH_RES=2, EM_TANH_OUT=6 };

__device__ __forceinline__ us f2bf(float f){
    unsigned int u = __float_as_uint(f);
    u += 0x7fffu + ((u >> 16) & 1u);
    return (us)(u >> 16);
}
__device__ __forceinline__ float bf2f(us h){
    return __uint_as_float(((unsigned int)h) << 16);
}
__device__ __forceinline__ void split_store(float v, us* ph, us* pl, size_t idx){
    us hh = f2bf(v); ph[idx] = hh; pl[idx] = f2bf(v - bf2f(hh));
}

// ---- preprocessing: split x + zero barrier counter ----
__global__ __launch_bounds__(256) void xsplit(const float* __restrict__ src,
                                              us* __restrict__ h, us* __restrict__ l,
                                              int n, unsigned* ctr){
    if (blockIdx.x == 0 && threadIdx.x == 0) *ctr = 0u;
    int i = blockIdx.x * 256 + threadIdx.x;
    if (i < n){
        float v = src[i];
        us hh = f2bf(v);
        h[i] = hh;
        l[i] = f2bf(v - bf2f(hh));
    }
}

// ---- preprocessing: all weight transpose+splits in ONE kernel ----
struct WsDesc { const float* src; us* h; us* l; int K; int N; int tile0; };
struct WsTable { WsDesc d[22]; };

__global__ __launch_bounds__(256) void wsplit_all(WsTable T){
    __shared__ float tile[32][33];
    const int t = blockIdx.x;
    int mi = 0;
    #pragma unroll 1
    for (int i = 1; i < 22; ++i) if (t >= T.d[i].tile0) mi = i;  // sentinels: tile0=INT_MAX
    const WsDesc dd = T.d[mi];
    const int local = t - dd.tile0;
    const int tilesx = dd.K >> 5;
    const int k0 = (local % tilesx) * 32;
    const int n0 = (local / tilesx) * 32;
    const int tt = threadIdx.x;
    const int r = tt >> 3;
    const int c4 = (tt & 7) * 4;
    const float4 v = *(const float4*)&dd.src[(size_t)(k0 + r) * dd.N + n0 + c4];
    tile[r][c4+0] = v.x; tile[r][c4+1] = v.y; tile[r][c4+2] = v.z; tile[r][c4+3] = v.w;
    __syncthreads();
    ushort4 hh, ll;
    #pragma unroll
    for (int j = 0; j < 4; ++j){
        float x = tile[c4 + j][r];
        us hb = f2bf(x);
        ((us*)&hh)[j] = hb;
        ((us*)&ll)[j] = f2bf(x - bf2f(hb));
    }
    *(ushort4*)&dd.h[(size_t)(n0 + r) * dd.K + k0 + c4] = hh;
    *(ushort4*)&dd.l[(size_t)(n0 + r) * dd.K + k0 + c4] = ll;
}

// ---- small GEMMs for input/output MLP (validated round-2 kernel) ----
__global__ __launch_bounds__(128) void gemm3p(
    const us* __restrict__ Ah, const us* __restrict__ Al,
    const us* __restrict__ Bh, const us* __restrict__ Bl,
    const float* __restrict__ bias,
    int M, int N, int K, int mode,
    us* __restrict__ outh, us* __restrict__ outl,
    float* outf, const float* res32)
{
    __shared__ us Ash[32][72];
    __shared__ us Asl[32][72];
    __shared__ us Bsh[64][72];
    __shared__ us Bsl[64][72];

    const int tid  = threadIdx.x;
    const int lane = tid & 63;
    const int w    = tid >> 6;
    const int m0   = blockIdx.y * 32;
    const int n0   = blockIdx.x * 64;

    f32x16 accA, accB;
    #pragma unroll
    for (int i = 0; i < 16; ++i){ accA[i] = 0.f; accB[i] = 0.f; }

    uint4 rAh[2], rAl[2], rBh[4], rBl[4];
    auto stage_load = [&](int k0){
        #pragma unroll
        for (int p = 0; p < 2; ++p){
            int id = p * 128 + tid; int r = id >> 3; int c = (id & 7) * 8;
            size_t off = (size_t)(m0 + r) * K + k0 + c;
            rAh[p] = *(const uint4*)&Ah[off];
            rAl[p] = *(const uint4*)&Al[off];
        }
        #pragma unroll
        for (int p = 0; p < 4; ++p){
            int id = p * 128 + tid; int r = id >> 3; int c = (id & 7) * 8;
            size_t off = (size_t)(n0 + r) * K + k0 + c;
            rBh[p] = *(const uint4*)&Bh[off];
            rBl[p] = *(const uint4*)&Bl[off];
        }
    };
    auto stage_write = [&](){
        #pragma unroll
        for (int p = 0; p < 2; ++p){
            int id = p * 128 + tid; int r = id >> 3; int c = (id & 7) * 8;
            *(uint4*)&Ash[r][c] = rAh[p];
            *(uint4*)&Asl[r][c] = rAl[p];
        }
        #pragma unroll
        for (int p = 0; p < 4; ++p){
            int id = p * 128 + tid; int r = id >> 3; int c = (id & 7) * 8;
            *(uint4*)&Bsh[r][c] = rBh[p];
            *(uint4*)&Bsl[r][c] = rBl[p];
        }
    };

    stage_load(0);
    stage_write();
    __syncthreads();

    const int arow = lane & 31;
    const int brow = w * 32 + (lane & 31);
    const int g8   = (lane >> 5) * 8;

    for (int k0 = 0; k0 < K; k0 += 64){
        const bool more = (k0 + 64) < K;
        if (more) stage_load(k0 + 64);
        #pragma unroll
        for (int kc = 0; kc < 4; ++kc){
            const int koff = kc * 16 + g8;
            bf16x8 a_h = *(const bf16x8*)&Ash[arow][koff];
            bf16x8 a_l = *(const bf16x8*)&Asl[arow][koff];
            bf16x8 b_h = *(const bf16x8*)&Bsh[brow][koff];
            bf16x8 b_l = *(const bf16x8*)&Bsl[brow][koff];
            accA = __builtin_amdgcn_mfma_f32_32x32x16_bf16(a_h, b_h, accA, 0, 0, 0);
            accB = __builtin_amdgcn_mfma_f32_32x32x16_bf16(a_h, b_l, accB, 0, 0, 0);
            accB = __builtin_amdgcn_mfma_f32_32x32x16_bf16(a_l, b_h, accB, 0, 0, 0);
        }
        if (more){
            __syncthreads();
            stage_write();
            __syncthreads();
        }
    }

    const int col = n0 + w * 32 + (lane & 31);
    const float bc = bias[col];
    const int g4 = (lane >> 5) * 4;
    #pragma unroll
    for (int r = 0; r < 16; ++r){
        const int row = m0 + (r & 3) + 8 * (r >> 2) + g4;
        const size_t idx = (size_t)row * N + col;
        float z = accA[r] + accB[r] + bc;
        if (mode == EM_PLAIN_F32){
            outf[idx] = z;
        } else if (mode == EM_TANH){
            float t = tanhf(z);
            split_store(t, outh, outl, idx);
        } else if (mode == EM_TANH_RES){
            float t = tanhf(z) + res32[idx];
            outf[idx] = t;
            split_store(t, outh, outl, idx);
        } else { // EM_TANH_OUT
            outf[idx] = tanhf(z);
        }
    }
}

// ---- device-scope grid barrier ----
// Cache-maintenance ONCE per barrier, not per poll:
//   arrive: RELEASE fetch_add (one buffer_wbl2 -> my stores visible)
//   spin:   RELAXED atomic loads (no cache ops, just coherence-point reads)
//   exit:   one ACQUIRE agent fence (one buffer_inv) before releasing the block
__device__ __forceinline__ void grid_bar(unsigned* ctr, unsigned target){
    __syncthreads();
    if (threadIdx.x == 0){
        __hip_atomic_fetch_add(ctr, 1u, __ATOMIC_RELEASE, __HIP_MEMORY_SCOPE_AGENT);
        long long t0 = (long long)__builtin_amdgcn_s_memrealtime();
        while (__hip_atomic_load(ctr, __ATOMIC_RELAXED, __HIP_MEMORY_SCOPE_AGENT) < target){
            __builtin_amdgcn_s_sleep(8);
            if ((long long)__builtin_amdgcn_s_memrealtime() - t0 > 200000000LL) break; // safety: no hang
        }
        __builtin_amdgcn_fence(__ATOMIC_ACQUIRE, "agent");
    }
    __syncthreads();
}

// ---- the fused ODE mega-kernel ----
// 256 blocks (1/CU), 256 threads. Each block owns rows m0..m0+63 and a fixed
// column tile of every GEMM stage. XCD mapping: mrow tied to XCD so activation
// row-panels stay in the producing XCD's L2; weights stream from L3.
__global__ __launch_bounds__(256, 1) void fused_ode(
    const us* __restrict__ W1t_h, const us* __restrict__ W1t_l, const float* __restrict__ B1,
    const us* __restrict__ W2t_h, const us* __restrict__ W2t_l, const float* __restrict__ B2,
    const us* __restrict__ W3t_h, const us* __restrict__ W3t_l, const float* __restrict__ B3,
    us* __restrict__ yh,  us* __restrict__ yl,
    us* __restrict__ yth, us* __restrict__ ytl,
    us* __restrict__ a1h, us* __restrict__ a1l,
    us* __restrict__ a2h, us* __restrict__ a2l,
    float* __restrict__ y32, float* __restrict__ kacc,
    unsigned* ctr)
{
    __shared__ us smem[18432];   // 36,864 B: A(64x72 hi/lo) + B(64x72 hi/lo)
    us* Ash = smem;
    us* Asl = smem + 4608;
    us* Bsh = smem + 9216;
    us* Bsl = smem + 13824;

    const int tid  = threadIdx.x;
    const int lane = tid & 63;
    const int w    = tid >> 6;
    const int bid  = blockIdx.x;
    // bid bits: [2:0]=xcd, [3]=m-sub, [7:4]=ncol
    const int mrow = (bid & 7) * 2 + ((bid >> 3) & 1);   // 0..15
    const int ncol = bid >> 4;                            // 0..15
    const int m0  = mrow * 64;
    const int n0  = ncol * 64;
    const int n0c = ncol * 32;
    const float hs = 1.0f / (float)RKSTEPS;
    unsigned epoch = 0;

    // 64x64-tile 3-pass GEMM: A [64][sA] via Ahp/Alp (row m0 applied),
    // B [64][K] via Bhp/Blp (row n0 applied). acc in c0..c2.
    auto gemm64 = [&](const us* Ahp, const us* Alp, int sA,
                      const us* Bhp, const us* Blp, int K,
                      f32x16& c0, f32x16& c1, f32x16& c2){
        uint4 rAh[2], rAl[2], rBh[2], rBl[2];
        auto ld = [&](int k0){
            #pragma unroll
            for (int p = 0; p < 2; ++p){
                int id = p * 256 + tid; int rr = id >> 3; int cc = (id & 7) * 8;
                rAh[p] = *(const uint4*)&Ahp[(size_t)rr * sA + k0 + cc];
                rAl[p] = *(const uint4*)&Alp[(size_t)rr * sA + k0 + cc];
                rBh[p] = *(const uint4*)&Bhp[(size_t)rr * K + k0 + cc];
                rBl[p] = *(const uint4*)&Blp[(size_t)rr * K + k0 + cc];
            }
        };
        auto wr = [&](){
            #pragma unroll
            for (int p = 0; p < 2; ++p){
                int id = p * 256 + tid; int rr = id >> 3; int cc = (id & 7) * 8;
                *(uint4*)&Ash[rr * 72 + cc] = rAh[p];
                *(uint4*)&Asl[rr * 72 + cc] = rAl[p];
                *(uint4*)&Bsh[rr * 72 + cc] = rBh[p];
                *(uint4*)&Bsl[rr * 72 + cc] = rBl[p];
            }
        };
        const int aoff = ((w >> 1) * 32 + (lane & 31)) * 72;
        const int boff = ((w & 1)  * 32 + (lane & 31)) * 72;
        const int g8   = (lane >> 5) * 8;
        ld(0);
        for (int k0 = 0; k0 < K; k0 += 64){
            wr(); __syncthreads();
            if (k0 + 64 < K) ld(k0 + 64);
            #pragma unroll
            for (int kc = 0; kc < 4; ++kc){
                int ko = kc * 16 + g8;
                bf16x8 ah = *(const bf16x8*)&Ash[aoff + ko];
                bf16x8 al = *(const bf16x8*)&Asl[aoff + ko];
                bf16x8 bh = *(const bf16x8*)&Bsh[boff + ko];
                bf16x8 bl = *(const bf16x8*)&Bsl[boff + ko];
                c0 = __builtin_amdgcn_mfma_f32_32x32x16_bf16(ah, bh, c0, 0, 0, 0);
                c1 = __builtin_amdgcn_mfma_f32_32x32x16_bf16(ah, bl, c1, 0, 0, 0);
                c2 = __builtin_amdgcn_mfma_f32_32x32x16_bf16(al, bh, c2, 0, 0, 0);
            }
            __syncthreads();
        }
    };

    // 64x32-tile GEMM (stage C): B has 32 rows; waves 0,1 do MFMA (full K),
    // all 4 waves help stage. K=1024, sA=1024 fixed.
    auto gemmC = [&](const us* Ahp, const us* Alp,
                     const us* Bhp, const us* Blp,
                     f32x16& c0, f32x16& c1, f32x16& c2){
        uint4 rAh[2], rAl[2], rBh, rBl;
        auto ld = [&](int k0){
            #pragma unroll
            for (int p = 0; p < 2; ++p){
                int id = p * 256 + tid; int rr = id >> 3; int cc = (id & 7) * 8;
                rAh[p] = *(const uint4*)&Ahp[(size_t)rr * 1024 + k0 + cc];
                rAl[p] = *(const uint4*)&Alp[(size_t)rr * 1024 + k0 + cc];
            }
            { int rr = tid >> 3; int cc = (tid & 7) * 8;
              rBh = *(const uint4*)&Bhp[(size_t)rr * 1024 + k0 + cc];
              rBl = *(const uint4*)&Blp[(size_t)rr * 1024 + k0 + cc]; }
        };
        auto wr = [&](){
            #pragma unroll
            for (int p = 0; p < 2; ++p){
                int id = p * 256 + tid; int rr = id >> 3; int cc = (id & 7) * 8;
                *(uint4*)&Ash[rr * 72 + cc] = rAh[p];
                *(uint4*)&Asl[rr * 72 + cc] = rAl[p];
            }
            { int rr = tid >> 3; int cc = (tid & 7) * 8;
              *(uint4*)&Bsh[rr * 72 + cc] = rBh;
              *(uint4*)&Bsl[rr * 72 + cc] = rBl; }
        };
        const int aoff = ((w & 1) * 32 + (lane & 31)) * 72;
        const int boff = (lane & 31) * 72;
        const int g8   = (lane >> 5) * 8;
        ld(0);
        for (int k0 = 0; k0 < 1024; k0 += 64){
            wr(); __syncthreads();
            if (k0 + 64 < 1024) ld(k0 + 64);
            if (w < 2){
                #pragma unroll
                for (int kc = 0; kc < 4; ++kc){
                    int ko = kc * 16 + g8;
                    bf16x8 ah = *(const bf16x8*)&Ash[aoff + ko];
                    bf16x8 al = *(const bf16x8*)&Asl[aoff + ko];
                    bf16x8 bh = *(const bf16x8*)&Bsh[boff + ko];
                    bf16x8 bl = *(const bf16x8*)&Bsl[boff + ko];
                    c0 = __builtin_amdgcn_mfma_f32_32x32x16_bf16(ah, bh, c0, 0, 0, 0);
                    c1 = __builtin_amdgcn_mfma_f32_32x32x16_bf16(ah, bl, c1, 0, 0, 0);
                    c2 = __builtin_amdgcn_mfma_f32_32x32x16_bf16(al, bh, c2, 0, 0, 0);
                }
            }
            __syncthreads();
        }
    };

    #pragma unroll 1
    for (int L = 0; L < 5; ++L){
        const us* W1h = W1t_h + (size_t)L * 1024 * 512;
        const us* W1l = W1t_l + (size_t)L * 1024 * 512;
        const us* W2h = W2t_h + (size_t)L * 1024 * 1024;
        const us* W2l = W2t_l + (size_t)L * 1024 * 1024;
        const us* W3h = W3t_h + (size_t)L * 512 * 1024;
        const us* W3l = W3t_l + (size_t)L * 512 * 1024;
        const float* b1 = B1 + L * 1024;
        const float* b2 = B2 + L * 1024;
        const float* b3 = B3 + L * 512;

        #pragma unroll 1
        for (int st = 0; st < RKSTEPS; ++st){
            #pragma unroll 1
            for (int s = 0; s < 4; ++s){
                const us* inh = (s == 0) ? yh : yth;
                const us* inl = (s == 0) ? yl : ytl;

                // ---- stage A: a1 = tanh(in @ W1 + b1), tile 64x64, K=512
                {
                    f32x16 c0, c1, c2;
                    #pragma unroll
                    for (int i = 0; i < 16; ++i){ c0[i]=0.f; c1[i]=0.f; c2[i]=0.f; }
                    gemm64(inh + (size_t)m0 * 512, inl + (size_t)m0 * 512, 512,
                           W1h + (size_t)n0 * 512, W1l + (size_t)n0 * 512, 512,
                           c0, c1, c2);
                    const int col = n0 + (w & 1) * 32 + (lane & 31);
                    const float bb = b1[col];
                    const int rbase = m0 + (w >> 1) * 32 + 4 * (lane >> 5);
                    #pragma unroll
                    for (int r = 0; r < 16; ++r){
                        int row = rbase + (r & 3) + 8 * (r >> 2);
                        float z = c0[r] + c1[r] + c2[r] + bb;
                        split_store(tanhf(z), a1h, a1l, (size_t)row * 1024 + col);
                    }
                }
                ++epoch; grid_bar(ctr, epoch * NBLK);

                // ---- stage B: a2 = tanh(a1 @ W2 + b2), tile 64x64, K=1024
                {
                    f32x16 c0, c1, c2;
                    #pragma unroll
                    for (int i = 0; i < 16; ++i){ c0[i]=0.f; c1[i]=0.f; c2[i]=0.f; }
                    gemm64(a1h + (size_t)m0 * 1024, a1l + (size_t)m0 * 1024, 1024,
                           W2h + (size_t)n0 * 1024, W2l + (size_t)n0 * 1024, 1024,
                           c0, c1, c2);
                    const int col = n0 + (w & 1) * 32 + (lane & 31);
                    const float bb = b2[col];
                    const int rbase = m0 + (w >> 1) * 32 + 4 * (lane >> 5);
                    #pragma unroll
                    for (int r = 0; r < 16; ++r){
                        int row = rbase + (r & 3) + 8 * (r >> 2);
                        float z = c0[r] + c1[r] + c2[r] + bb;
                        split_store(tanhf(z), a2h, a2l, (size_t)row * 1024 + col);
                    }
                }
                ++epoch; grid_bar(ctr, epoch * NBLK);

                // ---- stage C: k = a2 @ W3 + b3, tile 64x32, RK update
                {
                    f32x16 c0, c1, c2;
                    #pragma unroll
                    for (int i = 0; i < 16; ++i){ c0[i]=0.f; c1[i]=0.f; c2[i]=0.f; }
                    gemmC(a2h + (size_t)m0 * 1024, a2l + (size_t)m0 * 1024,
                          W3h + (size_t)n0c * 1024, W3l + (size_t)n0c * 1024,
                          c0, c1, c2);
                    if (w < 2){
                        const int col = n0c + (lane & 31);
                        const float bb = b3[col];
                        const int rbase = m0 + (w & 1) * 32 + 4 * (lane >> 5);
                        #pragma unroll
                        for (int r = 0; r < 16; ++r){
                            int row = rbase + (r & 3) + 8 * (r >> 2);
                            size_t idx = (size_t)row * 512 + col;
                            float z = c0[r] + c1[r] + c2[r] + bb;
                            if (s == 0){
                                kacc[idx] = z;
                                split_store(y32[idx] + 0.5f * hs * z, yth, ytl, idx);
                            } else if (s == 3){
                                float yn = y32[idx] + (hs / 6.0f) * (kacc[idx] + z);
                                y32[idx] = yn;
                                split_store(yn, yh, yl, idx);
                            } else {
                                kacc[idx] += 2.0f * z;
                                float hc = (s == 1) ? 0.5f * hs : hs;
                                split_store(y32[idx] + hc * z, yth, ytl, idx);
                            }
                        }
                    }
                }
                ++epoch; grid_bar(ctr, epoch * NBLK);
            }
        }
    }
}

extern "C" void kernel_launch(void* const* d_in, const int* in_sizes, int n_in,
                              void* d_out, int out_size, void* d_ws, size_t ws_size,
                              hipStream_t stream)
{
    (void)in_sizes; (void)n_in; (void)out_size; (void)ws_size;
    const float* x   = (const float*)d_in[0];
    const float* Wi1 = (const float*)d_in[1];
    const float* bi1 = (const float*)d_in[2];
    const float* Wi2 = (const float*)d_in[3];
    const float* bi2 = (const float*)d_in[4];
    const float* Wr  = (const float*)d_in[5];
    const float* br  = (const float*)d_in[6];
    const float* oW1 = (const float*)d_in[7];
    const float* ob1 = (const float*)d_in[8];
    const float* oW2 = (const float*)d_in[9];
    const float* ob2 = (const float*)d_in[10];
    const float* oW3 = (const float*)d_in[11];
    const float* ob3 = (const float*)d_in[12];
    const float* Wo1 = (const float*)d_in[13];
    const float* bo1 = (const float*)d_in[14];
    const float* Wo2 = (const float*)d_in[15];
    const float* bo2 = (const float*)d_in[16];
    float* out = (float*)d_out;

    char* p = (char*)d_ws;
    auto alloc = [&](size_t bytes)->char*{ char* r = p; p += (bytes + 255) & ~(size_t)255; return r; };

    us* xh = (us*)alloc(1024*256*2);  us* xl = (us*)alloc(1024*256*2);
    us* Wi1th = (us*)alloc(512*256*2);  us* Wi1tl = (us*)alloc(512*256*2);
    us* Wi2th = (us*)alloc(512*512*2);  us* Wi2tl = (us*)alloc(512*512*2);
    us* Wrth  = (us*)alloc(512*256*2);  us* Wrtl  = (us*)alloc(512*256*2);
    us* oW1th = (us*)alloc(5ull*1024*512*2);  us* oW1tl = (us*)alloc(5ull*1024*512*2);
    us* oW2th = (us*)alloc(5ull*1024*1024*2); us* oW2tl = (us*)alloc(5ull*1024*1024*2);
    us* oW3th = (us*)alloc(5ull*512*1024*2);  us* oW3tl = (us*)alloc(5ull*512*1024*2);
    us* Wo1th = (us*)alloc(512*512*2);  us* Wo1tl = (us*)alloc(512*512*2);
    us* Wo2th = (us*)alloc(128*512*2);  us* Wo2tl = (us*)alloc(128*512*2);
    us* t1h = (us*)alloc(1024ull*512*2);  us* t1l = (us*)alloc(1024ull*512*2);   // MLP temps [1024][512]
    us* a1h = (us*)alloc(1024ull*1024*2); us* a1l = (us*)alloc(1024ull*1024*2);
    us* a2h = (us*)alloc(1024ull*1024*2); us* a2l = (us*)alloc(1024ull*1024*2);
    us* yh  = (us*)alloc(1024ull*512*2);  us* yl  = (us*)alloc(1024ull*512*2);
    us* yth = (us*)alloc(1024ull*512*2);  us* ytl = (us*)alloc(1024ull*512*2);
    float* y32  = (float*)alloc(1024ull*512*4);
    float* kacc = (float*)alloc(1024ull*512*4);   // also used as rres in input block
    unsigned* ctr = (unsigned*)alloc(256);
    float* rres = kacc;  // alias: rres consumed before kacc's first RK write

    // ---- preprocessing (2 dispatches) ----
    hipLaunchKernelGGL(xsplit, dim3(1024), dim3(256), 0, stream, x, xh, xl, 1024*256, ctr);

    WsTable T;
    for (int i = 0; i < 22; ++i){
        T.d[i].src = nullptr; T.d[i].h = nullptr; T.d[i].l = nullptr;
        T.d[i].K = 32; T.d[i].N = 32; T.d[i].tile0 = 0x7fffffff;  // sentinel: never selected
    }
    int tile_acc = 0, di = 0;
    auto addW = [&](const float* W, us* th, us* tl, int K, int N){
        T.d[di].src = W; T.d[di].h = th; T.d[di].l = tl;
        T.d[di].K = K; T.d[di].N = N; T.d[di].tile0 = tile_acc;
        tile_acc += (K/32) * (N/32); ++di;
    };
    addW(Wi1, Wi1th, Wi1tl, 256, 512);
    addW(Wi2, Wi2th, Wi2tl, 512, 512);
    addW(Wr,  Wrth,  Wrtl,  256, 512);
    for (int L = 0; L < 5; ++L){
        addW(oW1 + (size_t)L*512*1024,  oW1th + (size_t)L*1024*512,  oW1tl + (size_t)L*1024*512,  512, 1024);
        addW(oW2 + (size_t)L*1024*1024, oW2th + (size_t)L*1024*1024, oW2tl + (size_t)L*1024*1024, 1024, 1024);
        addW(oW3 + (size_t)L*1024*512,  oW3th + (size_t)L*512*1024,  oW3tl + (size_t)L*512*1024,  1024, 512);
    }
    addW(Wo1, Wo1th, Wo1tl, 512, 512);
    addW(Wo2, Wo2th, Wo2tl, 512, 128);
    hipLaunchKernelGGL(wsplit_all, dim3(tile_acc), dim3(256), 0, stream, T);

    auto G = [&](const us* ah, const us* al, const us* bh, const us* bl,
                 const float* bias, int N, int K, int mode,
                 us* oh, us* ol, float* of, const float* rs){
        dim3 grid(N/64, BATCH/32);
        hipLaunchKernelGGL(gemm3p, grid, dim3(128), 0, stream,
                           ah, al, bh, bl, bias, BATCH, N, K, mode, oh, ol, of, rs);
    };

    // ---- input block (3 dispatches) ----
    G(xh, xl, Wrth, Wrtl, br, 512, 256, EM_PLAIN_F32, nullptr, nullptr, rres, nullptr);
    G(xh, xl, Wi1th, Wi1tl, bi1, 512, 256, EM_TANH, t1h, t1l, nullptr, nullptr);
    G(t1h, t1l, Wi2th, Wi2tl, bi2, 512, 512, EM_TANH_RES, yh, yl, y32, rres);

    // ---- the entire 5-layer RK4 ODE stack (1 dispatch) ----
    hipLaunchKernelGGL(fused_ode, dim3(NBLK), dim3(256), 0, stream,
                       oW1th, oW1tl, ob1, oW2th, oW2tl, ob2, oW3th, oW3tl, ob3,
                       yh, yl, yth, ytl, a1h, a1l, a2h, a2l, y32, kacc, ctr);

    // ---- output MLP (2 dispatches) ----
    G(yh, yl, Wo1th, Wo1tl, bo1, 512, 512, EM_TANH, t1h, t1l, nullptr, nullptr);
    G(t1h, t1l, Wo2th, Wo2tl, bo2, 128, 512, EM_TANH_OUT, nullptr, nullptr, out, nullptr);
}

// Round 7
// 35912.839 us; speedup vs baseline: 1.8601x; 1.5539x over previous
//
#include <hip/hip_runtime.h>
#include <hip/hip_bf16.h>
#include <math.h>

#define BATCH 1024
#define RKSTEPS 16

typedef unsigned short us;
typedef __bf16 bf16x8 __attribute__((ext_vector_type(8)));
typedef float f32x16 __attribute__((ext_vector_type(16)));

enum { EM_PLAIN_F32=0, EM_TANH=1, EM_TANH_RES=2, EM_TANH_OUT=6 };

__device__ __forceinline__ us f2bf(float f){
    unsigned int u = __float_as_uint(f);
    u += 0x7fffu + ((u >> 16) & 1u);
    return (us)(u >> 16);
}
__device__ __forceinline__ float bf2f(us h){
    return __uint_as_float(((unsigned int)h) << 16);
}
__device__ __forceinline__ void split_store(float v, us* ph, us* pl, size_t idx){
    us hh = f2bf(v); ph[idx] = hh; pl[idx] = f2bf(v - bf2f(hh));
}

// ---- preprocessing: split x + zero sync zone (flags + slot counters) ----
__global__ __launch_bounds__(256) void xsplit(const float* __restrict__ src,
                                              us* __restrict__ h, us* __restrict__ l,
                                              int n, unsigned* z, int zn){
    int i = blockIdx.x * 256 + threadIdx.x;
    if (i < zn) z[i] = 0u;
    if (i < n){
        float v = src[i];
        us hh = f2bf(v);
        h[i] = hh;
        l[i] = f2bf(v - bf2f(hh));
    }
}

// ---- preprocessing: all weight transpose+splits in ONE kernel ----
struct WsDesc { const float* src; us* h; us* l; int K; int N; int tile0; };
struct WsTable { WsDesc d[22]; };

__global__ __launch_bounds__(256) void wsplit_all(WsTable T){
    __shared__ float tile[32][33];
    const int t = blockIdx.x;
    int mi = 0;
    #pragma unroll 1
    for (int i = 1; i < 22; ++i) if (t >= T.d[i].tile0) mi = i;  // sentinels: tile0=INT_MAX
    const WsDesc dd = T.d[mi];
    const int local = t - dd.tile0;
    const int tilesx = dd.K >> 5;
    const int k0 = (local % tilesx) * 32;
    const int n0 = (local / tilesx) * 32;
    const int tt = threadIdx.x;
    const int r = tt >> 3;
    const int c4 = (tt & 7) * 4;
    const float4 v = *(const float4*)&dd.src[(size_t)(k0 + r) * dd.N + n0 + c4];
    tile[r][c4+0] = v.x; tile[r][c4+1] = v.y; tile[r][c4+2] = v.z; tile[r][c4+3] = v.w;
    __syncthreads();
    ushort4 hh, ll;
    #pragma unroll
    for (int j = 0; j < 4; ++j){
        float x = tile[c4 + j][r];
        us hb = f2bf(x);
        ((us*)&hh)[j] = hb;
        ((us*)&ll)[j] = f2bf(x - bf2f(hb));
    }
    *(ushort4*)&dd.h[(size_t)(n0 + r) * dd.K + k0 + c4] = hh;
    *(ushort4*)&dd.l[(size_t)(n0 + r) * dd.K + k0 + c4] = ll;
}

// ---- small GEMMs for input/output MLP (validated round-2 kernel) ----
__global__ __launch_bounds__(128) void gemm3p(
    const us* __restrict__ Ah, const us* __restrict__ Al,
    const us* __restrict__ Bh, const us* __restrict__ Bl,
    const float* __restrict__ bias,
    int M, int N, int K, int mode,
    us* __restrict__ outh, us* __restrict__ outl,
    float* outf, const float* res32)
{
    __shared__ us Ash[32][72];
    __shared__ us Asl[32][72];
    __shared__ us Bsh[64][72];
    __shared__ us Bsl[64][72];

    const int tid  = threadIdx.x;
    const int lane = tid & 63;
    const int w    = tid >> 6;
    const int m0   = blockIdx.y * 32;
    const int n0   = blockIdx.x * 64;

    f32x16 accA, accB;
    #pragma unroll
    for (int i = 0; i < 16; ++i){ accA[i] = 0.f; accB[i] = 0.f; }

    uint4 rAh[2], rAl[2], rBh[4], rBl[4];
    auto stage_load = [&](int k0){
        #pragma unroll
        for (int p = 0; p < 2; ++p){
            int id = p * 128 + tid; int r = id >> 3; int c = (id & 7) * 8;
            size_t off = (size_t)(m0 + r) * K + k0 + c;
            rAh[p] = *(const uint4*)&Ah[off];
            rAl[p] = *(const uint4*)&Al[off];
        }
        #pragma unroll
        for (int p = 0; p < 4; ++p){
            int id = p * 128 + tid; int r = id >> 3; int c = (id & 7) * 8;
            size_t off = (size_t)(n0 + r) * K + k0 + c;
            rBh[p] = *(const uint4*)&Bh[off];
            rBl[p] = *(const uint4*)&Bl[off];
        }
    };
    auto stage_write = [&](){
        #pragma unroll
        for (int p = 0; p < 2; ++p){
            int id = p * 128 + tid; int r = id >> 3; int c = (id & 7) * 8;
            *(uint4*)&Ash[r][c] = rAh[p];
            *(uint4*)&Asl[r][c] = rAl[p];
        }
        #pragma unroll
        for (int p = 0; p < 4; ++p){
            int id = p * 128 + tid; int r = id >> 3; int c = (id & 7) * 8;
            *(uint4*)&Bsh[r][c] = rBh[p];
            *(uint4*)&Bsl[r][c] = rBl[p];
        }
    };

    stage_load(0);
    stage_write();
    __syncthreads();

    const int arow = lane & 31;
    const int brow = w * 32 + (lane & 31);
    const int g8   = (lane >> 5) * 8;

    for (int k0 = 0; k0 < K; k0 += 64){
        const bool more = (k0 + 64) < K;
        if (more) stage_load(k0 + 64);
        #pragma unroll
        for (int kc = 0; kc < 4; ++kc){
            const int koff = kc * 16 + g8;
            bf16x8 a_h = *(const bf16x8*)&Ash[arow][koff];
            bf16x8 a_l = *(const bf16x8*)&Asl[arow][koff];
            bf16x8 b_h = *(const bf16x8*)&Bsh[brow][koff];
            bf16x8 b_l = *(const bf16x8*)&Bsl[brow][koff];
            accA = __builtin_amdgcn_mfma_f32_32x32x16_bf16(a_h, b_h, accA, 0, 0, 0);
            accB = __builtin_amdgcn_mfma_f32_32x32x16_bf16(a_h, b_l, accB, 0, 0, 0);
            accB = __builtin_amdgcn_mfma_f32_32x32x16_bf16(a_l, b_h, accB, 0, 0, 0);
        }
        if (more){
            __syncthreads();
            stage_write();
            __syncthreads();
        }
    }

    const int col = n0 + w * 32 + (lane & 31);
    const float bc = bias[col];
    const int g4 = (lane >> 5) * 4;
    #pragma unroll
    for (int r = 0; r < 16; ++r){
        const int row = m0 + (r & 3) + 8 * (r >> 2) + g4;
        const size_t idx = (size_t)row * N + col;
        float z = accA[r] + accB[r] + bc;
        if (mode == EM_PLAIN_F32){
            outf[idx] = z;
        } else if (mode == EM_TANH){
            float t = tanhf(z);
            split_store(t, outh, outl, idx);
        } else if (mode == EM_TANH_RES){
            float t = tanhf(z) + res32[idx];
            outf[idx] = t;
            split_store(t, outh, outl, idx);
        } else { // EM_TANH_OUT
            outf[idx] = tanhf(z);
        }
    }
}

// ---- per-rowgroup (16 blocks, same XCD) flag barrier ----
// No wbl2 ever: producer stores are vmcnt-drained by __syncthreads (write-through
// L1 -> XCD L2). One relaxed-agent flag store to arrive; 16 lanes poll relaxed
// (no per-poll cache maintenance); ONE agent-acquire (buffer_inv) on exit:
// invalidates L1 + clean L2 lines (weights -> refetch from L3, budgeted);
// dirty activation lines survive in the shared XCD L2.
__device__ __forceinline__ void rg_bar(unsigned* flg, int rg, int cg, unsigned epoch){
    __syncthreads();
    if (threadIdx.x == 0){
        __builtin_amdgcn_fence(__ATOMIC_RELEASE, "workgroup");
        __hip_atomic_store(&flg[(rg * 16 + cg) * 64], epoch,
                           __ATOMIC_RELAXED, __HIP_MEMORY_SCOPE_AGENT);
    }
    if (threadIdx.x < 16){
        unsigned* f = &flg[(rg * 16 + (int)threadIdx.x) * 64];
        long long t0 = (long long)__builtin_amdgcn_s_memrealtime();
        while (__hip_atomic_load(f, __ATOMIC_RELAXED, __HIP_MEMORY_SCOPE_AGENT) < epoch){
            __builtin_amdgcn_s_sleep(4);
            if ((long long)__builtin_amdgcn_s_memrealtime() - t0 > 100000000LL) break; // no hang
        }
        __builtin_amdgcn_fence(__ATOMIC_ACQUIRE, "agent");
    }
    __syncthreads();
}

// ---- the fused ODE mega-kernel, XCD-local version ----
// 256 blocks, 1/CU (LDS-forced). Self-organize via HW_REG_XCC_ID + per-XCD slot
// counter: rowgroup rg = xcd*2 + slot/16 owns batch rows [rg*64, rg*64+64);
// colgroup cg = slot%16 owns a 64-col (32 for stage C) slice. All activation
// exchange is rowgroup-internal => same-XCD => stays in that XCD's L2.
__global__ __launch_bounds__(256, 1) void fused_ode(
    const us* __restrict__ W1t_h, const us* __restrict__ W1t_l, const float* __restrict__ B1,
    const us* __restrict__ W2t_h, const us* __restrict__ W2t_l, const float* __restrict__ B2,
    const us* __restrict__ W3t_h, const us* __restrict__ W3t_l, const float* __restrict__ B3,
    us* __restrict__ yh,  us* __restrict__ yl,
    us* __restrict__ yth, us* __restrict__ ytl,
    us* __restrict__ a1h, us* __restrict__ a1l,
    us* __restrict__ a2h, us* __restrict__ a2l,
    float* __restrict__ y32, float* __restrict__ kacc,
    unsigned* flg, unsigned* slotctr)
{
    __shared__ us smem[2][4][4608];   // [dbuf][Ah,Al,Wh,Wl][64*72] = 73,728 B
    __shared__ us pad_force[6144];    // +12,288 B => 86,016 B total: forces 1 block/CU
    __shared__ int sh_rg, sh_cg;

    const int tid  = threadIdx.x;
    const int lane = tid & 63;
    const int w    = tid >> 6;

    if (tid == 0){
        unsigned xcc;
        asm volatile("s_getreg_b32 %0, hwreg(HW_REG_XCC_ID)" : "=s"(xcc));
        xcc &= 7u;
        unsigned slot = __hip_atomic_fetch_add(&slotctr[xcc], 1u,
                          __ATOMIC_RELAXED, __HIP_MEMORY_SCOPE_AGENT) & 31u;
        sh_rg = (int)(xcc * 2u + (slot >> 4));
        sh_cg = (int)(slot & 15u);
    }
    __syncthreads();
    const int rg = sh_rg, cg = sh_cg;
    const int m0 = rg * 64;
    if (flg == nullptr) pad_force[tid] = 0;   // opaque guard: keeps pad_force alive

    const float hs = 1.0f / (float)RKSTEPS;
    unsigned epoch = 0;

    // 64x64-tile 3-pass GEMM: C[64][64] = A[64][K] @ W^T-slice. A,W pre-offset.
    auto gemm64 = [&](const us* Ah, const us* Al, const us* Wh, const us* Wl,
                      int K, f32x16& c0, f32x16& c1, f32x16& c2){
        uint4 rA[2][2], rW[2][2];
        auto ld = [&](int k0){
            #pragma unroll
            for (int p = 0; p < 2; ++p){
                int id = p * 256 + tid; int rr = id >> 3; int cc = (id & 7) * 8;
                size_t ao = (size_t)rr * K + k0 + cc;
                rA[p][0] = *(const uint4*)&Ah[ao];
                rA[p][1] = *(const uint4*)&Al[ao];
                rW[p][0] = *(const uint4*)&Wh[ao];
                rW[p][1] = *(const uint4*)&Wl[ao];
            }
        };
        auto wr = [&](int b){
            #pragma unroll
            for (int p = 0; p < 2; ++p){
                int id = p * 256 + tid; int rr = id >> 3; int cc = (id & 7) * 8;
                *(uint4*)&smem[b][0][rr * 72 + cc] = rA[p][0];
                *(uint4*)&smem[b][1][rr * 72 + cc] = rA[p][1];
                *(uint4*)&smem[b][2][rr * 72 + cc] = rW[p][0];
                *(uint4*)&smem[b][3][rr * 72 + cc] = rW[p][1];
            }
        };
        const int aoff = ((w >> 1) * 32 + (lane & 31)) * 72;
        const int boff = ((w & 1)  * 32 + (lane & 31)) * 72;
        const int g8   = (lane >> 5) * 8;
        const int nc   = K >> 6;
        ld(0); wr(0);
        for (int c = 0; c < nc; ++c){
            __syncthreads();
            if (c + 1 < nc) ld((c + 1) << 6);
            const int b = c & 1;
            #pragma unroll
            for (int kc = 0; kc < 4; ++kc){
                int ko = kc * 16 + g8;
                bf16x8 ah = *(const bf16x8*)&smem[b][0][aoff + ko];
                bf16x8 al = *(const bf16x8*)&smem[b][1][aoff + ko];
                bf16x8 bh = *(const bf16x8*)&smem[b][2][boff + ko];
                bf16x8 bl = *(const bf16x8*)&smem[b][3][boff + ko];
                c0 = __builtin_amdgcn_mfma_f32_32x32x16_bf16(ah, bh, c0, 0, 0, 0);
                c1 = __builtin_amdgcn_mfma_f32_32x32x16_bf16(ah, bl, c1, 0, 0, 0);
                c2 = __builtin_amdgcn_mfma_f32_32x32x16_bf16(al, bh, c2, 0, 0, 0);
            }
            if (c + 1 < nc) wr((c + 1) & 1);
        }
    };

    // 64x32-tile stage-C GEMM: waves 0,1 compute; all stage. K=1024.
    auto gemmC = [&](const us* Ah, const us* Al, const us* Wh, const us* Wl,
                     f32x16& c0, f32x16& c1, f32x16& c2){
        uint4 rA[2][2], rW[2];
        auto ld = [&](int k0){
            #pragma unroll
            for (int p = 0; p < 2; ++p){
                int id = p * 256 + tid; int rr = id >> 3; int cc = (id & 7) * 8;
                size_t ao = (size_t)rr * 1024 + k0 + cc;
                rA[p][0] = *(const uint4*)&Ah[ao];
                rA[p][1] = *(const uint4*)&Al[ao];
            }
            { int rr = tid >> 3; int cc = (tid & 7) * 8;
              size_t wo = (size_t)rr * 1024 + k0 + cc;
              rW[0] = *(const uint4*)&Wh[wo];
              rW[1] = *(const uint4*)&Wl[wo]; }
        };
        auto wr = [&](int b){
            #pragma unroll
            for (int p = 0; p < 2; ++p){
                int id = p * 256 + tid; int rr = id >> 3; int cc = (id & 7) * 8;
                *(uint4*)&smem[b][0][rr * 72 + cc] = rA[p][0];
                *(uint4*)&smem[b][1][rr * 72 + cc] = rA[p][1];
            }
            { int rr = tid >> 3; int cc = (tid & 7) * 8;
              *(uint4*)&smem[b][2][rr * 72 + cc] = rW[0];
              *(uint4*)&smem[b][3][rr * 72 + cc] = rW[1]; }
        };
        const int aoff = ((w & 1) * 32 + (lane & 31)) * 72;
        const int boff = (lane & 31) * 72;
        const int g8   = (lane >> 5) * 8;
        ld(0); wr(0);
        for (int c = 0; c < 16; ++c){
            __syncthreads();
            if (c < 15) ld((c + 1) << 6);
            const int b = c & 1;
            if (w < 2){
                #pragma unroll
                for (int kc = 0; kc < 4; ++kc){
                    int ko = kc * 16 + g8;
                    bf16x8 ah = *(const bf16x8*)&smem[b][0][aoff + ko];
                    bf16x8 al = *(const bf16x8*)&smem[b][1][aoff + ko];
                    bf16x8 bh = *(const bf16x8*)&smem[b][2][boff + ko];
                    bf16x8 bl = *(const bf16x8*)&smem[b][3][boff + ko];
                    c0 = __builtin_amdgcn_mfma_f32_32x32x16_bf16(ah, bh, c0, 0, 0, 0);
                    c1 = __builtin_amdgcn_mfma_f32_32x32x16_bf16(ah, bl, c1, 0, 0, 0);
                    c2 = __builtin_amdgcn_mfma_f32_32x32x16_bf16(al, bh, c2, 0, 0, 0);
                }
            }
            if (c < 15) wr((c + 1) & 1);
        }
    };

    #pragma unroll 1
    for (int L = 0; L < 5; ++L){
        const us* W1h = W1t_h + (size_t)L * 1024 * 512;
        const us* W1l = W1t_l + (size_t)L * 1024 * 512;
        const us* W2h = W2t_h + (size_t)L * 1024 * 1024;
        const us* W2l = W2t_l + (size_t)L * 1024 * 1024;
        const us* W3h = W3t_h + (size_t)L * 512 * 1024;
        const us* W3l = W3t_l + (size_t)L * 512 * 1024;
        const float* b1 = B1 + L * 1024;
        const float* b2 = B2 + L * 1024;
        const float* b3 = B3 + L * 512;

        #pragma unroll 1
        for (int st = 0; st < RKSTEPS; ++st){
            #pragma unroll 1
            for (int s = 0; s < 4; ++s){
                const us* inh = (s == 0) ? yh : yth;
                const us* inl = (s == 0) ? yl : ytl;

                // ---- stage A: a1[m0..+64][cg*64..+64] = tanh(in @ W1 + b1), K=512
                {
                    f32x16 c0, c1, c2;
                    #pragma unroll
                    for (int i = 0; i < 16; ++i){ c0[i]=0.f; c1[i]=0.f; c2[i]=0.f; }
                    gemm64(inh + (size_t)m0 * 512, inl + (size_t)m0 * 512,
                           W1h + (size_t)(cg * 64) * 512, W1l + (size_t)(cg * 64) * 512,
                           512, c0, c1, c2);
                    const int col = cg * 64 + (w & 1) * 32 + (lane & 31);
                    const float bb = b1[col];
                    const int rbase = m0 + (w >> 1) * 32 + 4 * (lane >> 5);
                    #pragma unroll
                    for (int r = 0; r < 16; ++r){
                        int row = rbase + (r & 3) + 8 * (r >> 2);
                        float z = c0[r] + c1[r] + c2[r] + bb;
                        split_store(tanhf(z), a1h, a1l, (size_t)row * 1024 + col);
                    }
                }
                ++epoch; rg_bar(flg, rg, cg, epoch);

                // ---- stage B: a2[..][cg*64..+64] = tanh(a1 @ W2 + b2), K=1024
                {
                    f32x16 c0, c1, c2;
                    #pragma unroll
                    for (int i = 0; i < 16; ++i){ c0[i]=0.f; c1[i]=0.f; c2[i]=0.f; }
                    gemm64(a1h + (size_t)m0 * 1024, a1l + (size_t)m0 * 1024,
                           W2h + (size_t)(cg * 64) * 1024, W2l + (size_t)(cg * 64) * 1024,
                           1024, c0, c1, c2);
                    const int col = cg * 64 + (w & 1) * 32 + (lane & 31);
                    const float bb = b2[col];
                    const int rbase = m0 + (w >> 1) * 32 + 4 * (lane >> 5);
                    #pragma unroll
                    for (int r = 0; r < 16; ++r){
                        int row = rbase + (r & 3) + 8 * (r >> 2);
                        float z = c0[r] + c1[r] + c2[r] + bb;
                        split_store(tanhf(z), a2h, a2l, (size_t)row * 1024 + col);
                    }
                }
                ++epoch; rg_bar(flg, rg, cg, epoch);

                // ---- stage C: k[..][cg*32..+32] = a2 @ W3 + b3, RK update
                {
                    f32x16 c0, c1, c2;
                    #pragma unroll
                    for (int i = 0; i < 16; ++i){ c0[i]=0.f; c1[i]=0.f; c2[i]=0.f; }
                    gemmC(a2h + (size_t)m0 * 1024, a2l + (size_t)m0 * 1024,
                          W3h + (size_t)(cg * 32) * 1024, W3l + (size_t)(cg * 32) * 1024,
                          c0, c1, c2);
                    if (w < 2){
                        const int col = cg * 32 + (lane & 31);
                        const float bb = b3[col];
                        const int rbase = m0 + w * 32 + 4 * (lane >> 5);
                        #pragma unroll
                        for (int r = 0; r < 16; ++r){
                            int row = rbase + (r & 3) + 8 * (r >> 2);
                            size_t idx = (size_t)row * 512 + col;
                            float z = c0[r] + c1[r] + c2[r] + bb;
                            if (s == 0){
                                kacc[idx] = z;
                                split_store(y32[idx] + 0.5f * hs * z, yth, ytl, idx);
                            } else if (s == 3){
                                float yn = y32[idx] + (hs / 6.0f) * (kacc[idx] + z);
                                y32[idx] = yn;
                                split_store(yn, yh, yl, idx);
                            } else {
                                kacc[idx] += 2.0f * z;
                                float hc = (s == 1) ? 0.5f * hs : hs;
                                split_store(y32[idx] + hc * z, yth, ytl, idx);
                            }
                        }
                    }
                }
                ++epoch; rg_bar(flg, rg, cg, epoch);
            }
        }
    }
}

extern "C" void kernel_launch(void* const* d_in, const int* in_sizes, int n_in,
                              void* d_out, int out_size, void* d_ws, size_t ws_size,
                              hipStream_t stream)
{
    (void)in_sizes; (void)n_in; (void)out_size; (void)ws_size;
    const float* x   = (const float*)d_in[0];
    const float* Wi1 = (const float*)d_in[1];
    const float* bi1 = (const float*)d_in[2];
    const float* Wi2 = (const float*)d_in[3];
    const float* bi2 = (const float*)d_in[4];
    const float* Wr  = (const float*)d_in[5];
    const float* br  = (const float*)d_in[6];
    const float* oW1 = (const float*)d_in[7];
    const float* ob1 = (const float*)d_in[8];
    const float* oW2 = (const float*)d_in[9];
    const float* ob2 = (const float*)d_in[10];
    const float* oW3 = (const float*)d_in[11];
    const float* ob3 = (const float*)d_in[12];
    const float* Wo1 = (const float*)d_in[13];
    const float* bo1 = (const float*)d_in[14];
    const float* Wo2 = (const float*)d_in[15];
    const float* bo2 = (const float*)d_in[16];
    float* out = (float*)d_out;

    char* p = (char*)d_ws;
    auto alloc = [&](size_t bytes)->char*{ char* r = p; p += (bytes + 255) & ~(size_t)255; return r; };

    us* xh = (us*)alloc(1024*256*2);  us* xl = (us*)alloc(1024*256*2);
    us* Wi1th = (us*)alloc(512*256*2);  us* Wi1tl = (us*)alloc(512*256*2);
    us* Wi2th = (us*)alloc(512*512*2);  us* Wi2tl = (us*)alloc(512*512*2);
    us* Wrth  = (us*)alloc(512*256*2);  us* Wrtl  = (us*)alloc(512*256*2);
    us* oW1th = (us*)alloc(5ull*1024*512*2);  us* oW1tl = (us*)alloc(5ull*1024*512*2);
    us* oW2th = (us*)alloc(5ull*1024*1024*2); us* oW2tl = (us*)alloc(5ull*1024*1024*2);
    us* oW3th = (us*)alloc(5ull*512*1024*2);  us* oW3tl = (us*)alloc(5ull*512*1024*2);
    us* Wo1th = (us*)alloc(512*512*2);  us* Wo1tl = (us*)alloc(512*512*2);
    us* Wo2th = (us*)alloc(128*512*2);  us* Wo2tl = (us*)alloc(128*512*2);
    us* t1h = (us*)alloc(1024ull*512*2);  us* t1l = (us*)alloc(1024ull*512*2);   // MLP temps
    us* a1h = (us*)alloc(1024ull*1024*2); us* a1l = (us*)alloc(1024ull*1024*2);
    us* a2h = (us*)alloc(1024ull*1024*2); us* a2l = (us*)alloc(1024ull*1024*2);
    us* yh  = (us*)alloc(1024ull*512*2);  us* yl  = (us*)alloc(1024ull*512*2);
    us* yth = (us*)alloc(1024ull*512*2);  us* ytl = (us*)alloc(1024ull*512*2);
    float* y32  = (float*)alloc(1024ull*512*4);
    float* kacc = (float*)alloc(1024ull*512*4);   // also rres in input block
    unsigned* syncz = (unsigned*)alloc((16*16*64 + 16) * 4);  // flags + slot counters
    unsigned* flg = syncz;
    unsigned* slotctr = syncz + 16*16*64;
    float* rres = kacc;  // alias: rres consumed before kacc's first RK write

    const int ZN = 16*16*64 + 16;

    // ---- preprocessing (2 dispatches) ----
    hipLaunchKernelGGL(xsplit, dim3(1024), dim3(256), 0, stream, x, xh, xl, 1024*256, syncz, ZN);

    WsTable T;
    for (int i = 0; i < 22; ++i){
        T.d[i].src = nullptr; T.d[i].h = nullptr; T.d[i].l = nullptr;
        T.d[i].K = 32; T.d[i].N = 32; T.d[i].tile0 = 0x7fffffff;  // sentinel
    }
    int tile_acc = 0, di = 0;
    auto addW = [&](const float* W, us* th, us* tl, int K, int N){
        T.d[di].src = W; T.d[di].h = th; T.d[di].l = tl;
        T.d[di].K = K; T.d[di].N = N; T.d[di].tile0 = tile_acc;
        tile_acc += (K/32) * (N/32); ++di;
    };
    addW(Wi1, Wi1th, Wi1tl, 256, 512);
    addW(Wi2, Wi2th, Wi2tl, 512, 512);
    addW(Wr,  Wrth,  Wrtl,  256, 512);
    for (int L = 0; L < 5; ++L){
        addW(oW1 + (size_t)L*512*1024,  oW1th + (size_t)L*1024*512,  oW1tl + (size_t)L*1024*512,  512, 1024);
        addW(oW2 + (size_t)L*1024*1024, oW2th + (size_t)L*1024*1024, oW2tl + (size_t)L*1024*1024, 1024, 1024);
        addW(oW3 + (size_t)L*1024*512,  oW3th + (size_t)L*512*1024,  oW3tl + (size_t)L*512*1024,  1024, 512);
    }
    addW(Wo1, Wo1th, Wo1tl, 512, 512);
    addW(Wo2, Wo2th, Wo2tl, 512, 128);
    hipLaunchKernelGGL(wsplit_all, dim3(tile_acc), dim3(256), 0, stream, T);

    auto G = [&](const us* ah, const us* al, const us* bh, const us* bl,
                 const float* bias, int N, int K, int mode,
                 us* oh, us* ol, float* of, const float* rs){
        dim3 grid(N/64, BATCH/32);
        hipLaunchKernelGGL(gemm3p, grid, dim3(128), 0, stream,
                           ah, al, bh, bl, bias, BATCH, N, K, mode, oh, ol, of, rs);
    };

    // ---- input block (3 dispatches) ----
    G(xh, xl, Wrth, Wrtl, br, 512, 256, EM_PLAIN_F32, nullptr, nullptr, rres, nullptr);
    G(xh, xl, Wi1th, Wi1tl, bi1, 512, 256, EM_TANH, t1h, t1l, nullptr, nullptr);
    G(t1h, t1l, Wi2th, Wi2tl, bi2, 512, 512, EM_TANH_RES, yh, yl, y32, rres);

    // ---- the entire 5-layer RK4 ODE stack (1 dispatch, XCD-local) ----
    hipLaunchKernelGGL(fused_ode, dim3(256), dim3(256), 0, stream,
                       oW1th, oW1tl, ob1, oW2th, oW2tl, ob2, oW3th, oW3tl, ob3,
                       yh, yl, yth, ytl, a1h, a1l, a2h, a2l, y32, kacc, flg, slotctr);

    // ---- output MLP (2 dispatches) ----
    G(yh, yl, Wo1th, Wo1tl, bo1, 512, 512, EM_TANH, t1h, t1l, nullptr, nullptr);
    G(t1h, t1l, Wo2th, Wo2tl, bo2, 128, 512, EM_TANH_OUT, nullptr, nullptr, out, nullptr);
}

// Round 9
// 34679.675 us; speedup vs baseline: 1.9263x; 1.0356x over previous
//
#include <hip/hip_runtime.h>
#include <hip/hip_bf16.h>
#include <math.h>

#define BATCH 1024
#define RKSTEPS 16

typedef unsigned short us;
typedef __bf16 bf16x8 __attribute__((ext_vector_type(8)));
typedef float f32x16 __attribute__((ext_vector_type(16)));

enum { EM_PLAIN_F32=0, EM_TANH=1, EM_TANH_RES=2, EM_TANH_OUT=6 };

__device__ __forceinline__ us f2bf(float f){
    unsigned int u = __float_as_uint(f);
    u += 0x7fffu + ((u >> 16) & 1u);
    return (us)(u >> 16);
}
__device__ __forceinline__ float bf2f(us h){
    return __uint_as_float(((unsigned int)h) << 16);
}
__device__ __forceinline__ void split_store(float v, us* ph, us* pl, size_t idx){
    us hh = f2bf(v); ph[idx] = hh; pl[idx] = f2bf(v - bf2f(hh));
}

// ---- preprocessing: split x + zero sync zone (flags + slot counters) ----
__global__ __launch_bounds__(256) void xsplit(const float* __restrict__ src,
                                              us* __restrict__ h, us* __restrict__ l,
                                              int n, unsigned* z, int zn){
    int i = blockIdx.x * 256 + threadIdx.x;
    if (i < zn) z[i] = 0u;
    if (i < n){
        float v = src[i];
        us hh = f2bf(v);
        h[i] = hh;
        l[i] = f2bf(v - bf2f(hh));
    }
}

// ---- preprocessing: all weight transpose+splits in ONE kernel ----
struct WsDesc { const float* src; us* h; us* l; int K; int N; int tile0; };
struct WsTable { WsDesc d[22]; };

__global__ __launch_bounds__(256) void wsplit_all(WsTable T){
    __shared__ float tile[32][33];
    const int t = blockIdx.x;
    int mi = 0;
    #pragma unroll 1
    for (int i = 1; i < 22; ++i) if (t >= T.d[i].tile0) mi = i;  // sentinels: tile0=INT_MAX
    const WsDesc dd = T.d[mi];
    const int local = t - dd.tile0;
    const int tilesx = dd.K >> 5;
    const int k0 = (local % tilesx) * 32;
    const int n0 = (local / tilesx) * 32;
    const int tt = threadIdx.x;
    const int r = tt >> 3;
    const int c4 = (tt & 7) * 4;
    const float4 v = *(const float4*)&dd.src[(size_t)(k0 + r) * dd.N + n0 + c4];
    tile[r][c4+0] = v.x; tile[r][c4+1] = v.y; tile[r][c4+2] = v.z; tile[r][c4+3] = v.w;
    __syncthreads();
    ushort4 hh, ll;
    #pragma unroll
    for (int j = 0; j < 4; ++j){
        float x = tile[c4 + j][r];
        us hb = f2bf(x);
        ((us*)&hh)[j] = hb;
        ((us*)&ll)[j] = f2bf(x - bf2f(hb));
    }
    *(ushort4*)&dd.h[(size_t)(n0 + r) * dd.K + k0 + c4] = hh;
    *(ushort4*)&dd.l[(size_t)(n0 + r) * dd.K + k0 + c4] = ll;
}

// ---- small GEMMs for input/output MLP (validated round-2 kernel) ----
__global__ __launch_bounds__(128) void gemm3p(
    const us* __restrict__ Ah, const us* __restrict__ Al,
    const us* __restrict__ Bh, const us* __restrict__ Bl,
    const float* __restrict__ bias,
    int M, int N, int K, int mode,
    us* __restrict__ outh, us* __restrict__ outl,
    float* outf, const float* res32)
{
    __shared__ us Ash[32][72];
    __shared__ us Asl[32][72];
    __shared__ us Bsh[64][72];
    __shared__ us Bsl[64][72];

    const int tid  = threadIdx.x;
    const int lane = tid & 63;
    const int w    = tid >> 6;
    const int m0   = blockIdx.y * 32;
    const int n0   = blockIdx.x * 64;

    f32x16 accA, accB;
    #pragma unroll
    for (int i = 0; i < 16; ++i){ accA[i] = 0.f; accB[i] = 0.f; }

    uint4 rAh[2], rAl[2], rBh[4], rBl[4];
    auto stage_load = [&](int k0){
        #pragma unroll
        for (int p = 0; p < 2; ++p){
            int id = p * 128 + tid; int r = id >> 3; int c = (id & 7) * 8;
            size_t off = (size_t)(m0 + r) * K + k0 + c;
            rAh[p] = *(const uint4*)&Ah[off];
            rAl[p] = *(const uint4*)&Al[off];
        }
        #pragma unroll
        for (int p = 0; p < 4; ++p){
            int id = p * 128 + tid; int r = id >> 3; int c = (id & 7) * 8;
            size_t off = (size_t)(n0 + r) * K + k0 + c;
            rBh[p] = *(const uint4*)&Bh[off];
            rBl[p] = *(const uint4*)&Bl[off];
        }
    };
    auto stage_write = [&](){
        #pragma unroll
        for (int p = 0; p < 2; ++p){
            int id = p * 128 + tid; int r = id >> 3; int c = (id & 7) * 8;
            *(uint4*)&Ash[r][c] = rAh[p];
            *(uint4*)&Asl[r][c] = rAl[p];
        }
        #pragma unroll
        for (int p = 0; p < 4; ++p){
            int id = p * 128 + tid; int r = id >> 3; int c = (id & 7) * 8;
            *(uint4*)&Bsh[r][c] = rBh[p];
            *(uint4*)&Bsl[r][c] = rBl[p];
        }
    };

    stage_load(0);
    stage_write();
    __syncthreads();

    const int arow = lane & 31;
    const int brow = w * 32 + (lane & 31);
    const int g8   = (lane >> 5) * 8;

    for (int k0 = 0; k0 < K; k0 += 64){
        const bool more = (k0 + 64) < K;
        if (more) stage_load(k0 + 64);
        #pragma unroll
        for (int kc = 0; kc < 4; ++kc){
            const int koff = kc * 16 + g8;
            bf16x8 a_h = *(const bf16x8*)&Ash[arow][koff];
            bf16x8 a_l = *(const bf16x8*)&Asl[arow][koff];
            bf16x8 b_h = *(const bf16x8*)&Bsh[brow][koff];
            bf16x8 b_l = *(const bf16x8*)&Bsl[brow][koff];
            accA = __builtin_amdgcn_mfma_f32_32x32x16_bf16(a_h, b_h, accA, 0, 0, 0);
            accB = __builtin_amdgcn_mfma_f32_32x32x16_bf16(a_h, b_l, accB, 0, 0, 0);
            accB = __builtin_amdgcn_mfma_f32_32x32x16_bf16(a_l, b_h, accB, 0, 0, 0);
        }
        if (more){
            __syncthreads();
            stage_write();
            __syncthreads();
        }
    }

    const int col = n0 + w * 32 + (lane & 31);
    const float bc = bias[col];
    const int g4 = (lane >> 5) * 4;
    #pragma unroll
    for (int r = 0; r < 16; ++r){
        const int row = m0 + (r & 3) + 8 * (r >> 2) + g4;
        const size_t idx = (size_t)row * N + col;
        float z = accA[r] + accB[r] + bc;
        if (mode == EM_PLAIN_F32){
            outf[idx] = z;
        } else if (mode == EM_TANH){
            float t = tanhf(z);
            split_store(t, outh, outl, idx);
        } else if (mode == EM_TANH_RES){
            float t = tanhf(z) + res32[idx];
            outf[idx] = t;
            split_store(t, outh, outl, idx);
        } else { // EM_TANH_OUT
            outf[idx] = tanhf(z);
        }
    }
}

// ---- per-rowgroup (16 blocks, same XCD) flag barrier ----
// Same flag mechanism as the VERIFIED round-7 barrier (HIP relaxed-agent
// atomics). ONLY change: exit fence is plain buffer_inv (vector-L1-only
// invalidate) instead of fence(ACQUIRE,"agent") (which emitted buffer_inv
// sc1 => device-wide clean-line invalidation, evicting weights from L2/L3
// every barrier -> the 12.9 GB refetch seen in round 7). Correct because
// all cross-block communication is same-XCD: the shared XCD L2 is the
// coherence point; L1 is write-through (no dirty lines to lose).
__device__ __forceinline__ void rg_bar(unsigned* flg, int rg, int cg, unsigned epoch){
    __syncthreads();
    if (threadIdx.x == 0){
        __builtin_amdgcn_fence(__ATOMIC_RELEASE, "workgroup");
        __hip_atomic_store(&flg[(rg * 16 + cg) * 64], epoch,
                           __ATOMIC_RELAXED, __HIP_MEMORY_SCOPE_AGENT);
    }
    if (threadIdx.x < 16){
        unsigned* f = &flg[(rg * 16 + (int)threadIdx.x) * 64];
        long long t0 = (long long)__builtin_amdgcn_s_memrealtime();
        while (__hip_atomic_load(f, __ATOMIC_RELAXED, __HIP_MEMORY_SCOPE_AGENT) < epoch){
            __builtin_amdgcn_s_sleep(2);
            // ~10ms safety: a total sync failure finishes in ~10s and reports,
            // instead of wedging the harness.
            if ((long long)__builtin_amdgcn_s_memrealtime() - t0 > 1000000LL) break;
        }
        asm volatile("buffer_inv" ::: "memory");   // L1-only invalidate
    }
    __syncthreads();
}

// ---- the fused ODE mega-kernel, XCD-local version ----
// 256 blocks, 1/CU (LDS-forced). Self-organize via HW_REG_XCC_ID + per-XCD slot
// counter: rowgroup rg = xcd*2 + slot/16 owns batch rows [rg*64, rg*64+64);
// colgroup cg = slot%16 owns a 64-col (32 for stage C) slice. All activation
// exchange is rowgroup-internal => same-XCD => stays in that XCD's L2.
__global__ __launch_bounds__(256, 1) void fused_ode(
    const us* __restrict__ W1t_h, const us* __restrict__ W1t_l, const float* __restrict__ B1,
    const us* __restrict__ W2t_h, const us* __restrict__ W2t_l, const float* __restrict__ B2,
    const us* __restrict__ W3t_h, const us* __restrict__ W3t_l, const float* __restrict__ B3,
    us* __restrict__ yh,  us* __restrict__ yl,
    us* __restrict__ yth, us* __restrict__ ytl,
    us* __restrict__ a1h, us* __restrict__ a1l,
    us* __restrict__ a2h, us* __restrict__ a2l,
    float* __restrict__ y32, float* __restrict__ kacc,
    unsigned* flg, unsigned* slotctr)
{
    __shared__ us smem[2][4][4608];   // [dbuf][Ah,Al,Wh,Wl][64*72] = 73,728 B
    __shared__ us pad_force[6144];    // LDS pad (dead-store-eliminated; 74,240B still => 1 block/CU w/ 256 VGPR)
    __shared__ int sh_rg, sh_cg;

    const int tid  = threadIdx.x;
    const int lane = tid & 63;
    const int w    = tid >> 6;

    if (tid == 0){
        unsigned xcc;
        asm volatile("s_getreg_b32 %0, hwreg(HW_REG_XCC_ID)" : "=s"(xcc));
        xcc &= 7u;
        unsigned slot = __hip_atomic_fetch_add(&slotctr[xcc], 1u,
                          __ATOMIC_RELAXED, __HIP_MEMORY_SCOPE_AGENT) & 31u;
        sh_rg = (int)(xcc * 2u + (slot >> 4));
        sh_cg = (int)(slot & 15u);
    }
    __syncthreads();
    const int rg = sh_rg, cg = sh_cg;
    const int m0 = rg * 64;
    if (flg == nullptr) pad_force[tid] = 0;   // opaque guard

    const float hs = 1.0f / (float)RKSTEPS;
    unsigned epoch = 0;

    // 64x64-tile 3-pass GEMM: C[64][64] = A[64][K] @ W^T-slice. A,W pre-offset.
    auto gemm64 = [&](const us* Ah, const us* Al, const us* Wh, const us* Wl,
                      int K, f32x16& c0, f32x16& c1, f32x16& c2){
        uint4 rA[2][2], rW[2][2];
        auto ld = [&](int k0){
            #pragma unroll
            for (int p = 0; p < 2; ++p){
                int id = p * 256 + tid; int rr = id >> 3; int cc = (id & 7) * 8;
                size_t ao = (size_t)rr * K + k0 + cc;
                rA[p][0] = *(const uint4*)&Ah[ao];
                rA[p][1] = *(const uint4*)&Al[ao];
                rW[p][0] = *(const uint4*)&Wh[ao];
                rW[p][1] = *(const uint4*)&Wl[ao];
            }
        };
        auto wr = [&](int b){
            #pragma unroll
            for (int p = 0; p < 2; ++p){
                int id = p * 256 + tid; int rr = id >> 3; int cc = (id & 7) * 8;
                *(uint4*)&smem[b][0][rr * 72 + cc] = rA[p][0];
                *(uint4*)&smem[b][1][rr * 72 + cc] = rA[p][1];
                *(uint4*)&smem[b][2][rr * 72 + cc] = rW[p][0];
                *(uint4*)&smem[b][3][rr * 72 + cc] = rW[p][1];
            }
        };
        const int aoff = ((w >> 1) * 32 + (lane & 31)) * 72;
        const int boff = ((w & 1)  * 32 + (lane & 31)) * 72;
        const int g8   = (lane >> 5) * 8;
        const int nc   = K >> 6;
        ld(0); wr(0);
        for (int c = 0; c < nc; ++c){
            __syncthreads();
            if (c + 1 < nc) ld((c + 1) << 6);
            const int b = c & 1;
            #pragma unroll
            for (int kc = 0; kc < 4; ++kc){
                int ko = kc * 16 + g8;
                bf16x8 ah = *(const bf16x8*)&smem[b][0][aoff + ko];
                bf16x8 al = *(const bf16x8*)&smem[b][1][aoff + ko];
                bf16x8 bh = *(const bf16x8*)&smem[b][2][boff + ko];
                bf16x8 bl = *(const bf16x8*)&smem[b][3][boff + ko];
                c0 = __builtin_amdgcn_mfma_f32_32x32x16_bf16(ah, bh, c0, 0, 0, 0);
                c1 = __builtin_amdgcn_mfma_f32_32x32x16_bf16(ah, bl, c1, 0, 0, 0);
                c2 = __builtin_amdgcn_mfma_f32_32x32x16_bf16(al, bh, c2, 0, 0, 0);
            }
            if (c + 1 < nc) wr((c + 1) & 1);
        }
    };

    // 64x32-tile stage-C GEMM: waves 0,1 compute; all stage. K=1024.
    auto gemmC = [&](const us* Ah, const us* Al, const us* Wh, const us* Wl,
                     f32x16& c0, f32x16& c1, f32x16& c2){
        uint4 rA[2][2], rW[2];
        auto ld = [&](int k0){
            #pragma unroll
            for (int p = 0; p < 2; ++p){
                int id = p * 256 + tid; int rr = id >> 3; int cc = (id & 7) * 8;
                size_t ao = (size_t)rr * 1024 + k0 + cc;
                rA[p][0] = *(const uint4*)&Ah[ao];
                rA[p][1] = *(const uint4*)&Al[ao];
            }
            { int rr = tid >> 3; int cc = (tid & 7) * 8;
              size_t wo = (size_t)rr * 1024 + k0 + cc;
              rW[0] = *(const uint4*)&Wh[wo];
              rW[1] = *(const uint4*)&Wl[wo]; }
        };
        auto wr = [&](int b){
            #pragma unroll
            for (int p = 0; p < 2; ++p){
                int id = p * 256 + tid; int rr = id >> 3; int cc = (id & 7) * 8;
                *(uint4*)&smem[b][0][rr * 72 + cc] = rA[p][0];
                *(uint4*)&smem[b][1][rr * 72 + cc] = rA[p][1];
            }
            { int rr = tid >> 3; int cc = (tid & 7) * 8;
              *(uint4*)&smem[b][2][rr * 72 + cc] = rW[0];
              *(uint4*)&smem[b][3][rr * 72 + cc] = rW[1]; }
        };
        const int aoff = ((w & 1) * 32 + (lane & 31)) * 72;
        const int boff = (lane & 31) * 72;
        const int g8   = (lane >> 5) * 8;
        ld(0); wr(0);
        for (int c = 0; c < 16; ++c){
            __syncthreads();
            if (c < 15) ld((c + 1) << 6);
            const int b = c & 1;
            if (w < 2){
                #pragma unroll
                for (int kc = 0; kc < 4; ++kc){
                    int ko = kc * 16 + g8;
                    bf16x8 ah = *(const bf16x8*)&smem[b][0][aoff + ko];
                    bf16x8 al = *(const bf16x8*)&smem[b][1][aoff + ko];
                    bf16x8 bh = *(const bf16x8*)&smem[b][2][boff + ko];
                    bf16x8 bl = *(const bf16x8*)&smem[b][3][boff + ko];
                    c0 = __builtin_amdgcn_mfma_f32_32x32x16_bf16(ah, bh, c0, 0, 0, 0);
                    c1 = __builtin_amdgcn_mfma_f32_32x32x16_bf16(ah, bl, c1, 0, 0, 0);
                    c2 = __builtin_amdgcn_mfma_f32_32x32x16_bf16(al, bh, c2, 0, 0, 0);
                }
            }
            if (c < 15) wr((c + 1) & 1);
        }
    };

    #pragma unroll 1
    for (int L = 0; L < 5; ++L){
        const us* W1h = W1t_h + (size_t)L * 1024 * 512;
        const us* W1l = W1t_l + (size_t)L * 1024 * 512;
        const us* W2h = W2t_h + (size_t)L * 1024 * 1024;
        const us* W2l = W2t_l + (size_t)L * 1024 * 1024;
        const us* W3h = W3t_h + (size_t)L * 512 * 1024;
        const us* W3l = W3t_l + (size_t)L * 512 * 1024;
        const float* b1 = B1 + L * 1024;
        const float* b2 = B2 + L * 1024;
        const float* b3 = B3 + L * 512;

        #pragma unroll 1
        for (int st = 0; st < RKSTEPS; ++st){
            #pragma unroll 1
            for (int s = 0; s < 4; ++s){
                const us* inh = (s == 0) ? yh : yth;
                const us* inl = (s == 0) ? yl : ytl;

                // ---- stage A: a1[m0..+64][cg*64..+64] = tanh(in @ W1 + b1), K=512
                {
                    f32x16 c0, c1, c2;
                    #pragma unroll
                    for (int i = 0; i < 16; ++i){ c0[i]=0.f; c1[i]=0.f; c2[i]=0.f; }
                    gemm64(inh + (size_t)m0 * 512, inl + (size_t)m0 * 512,
                           W1h + (size_t)(cg * 64) * 512, W1l + (size_t)(cg * 64) * 512,
                           512, c0, c1, c2);
                    const int col = cg * 64 + (w & 1) * 32 + (lane & 31);
                    const float bb = b1[col];
                    const int rbase = m0 + (w >> 1) * 32 + 4 * (lane >> 5);
                    #pragma unroll
                    for (int r = 0; r < 16; ++r){
                        int row = rbase + (r & 3) + 8 * (r >> 2);
                        float z = c0[r] + c1[r] + c2[r] + bb;
                        split_store(tanhf(z), a1h, a1l, (size_t)row * 1024 + col);
                    }
                }
                ++epoch; rg_bar(flg, rg, cg, epoch);

                // ---- stage B: a2[..][cg*64..+64] = tanh(a1 @ W2 + b2), K=1024
                {
                    f32x16 c0, c1, c2;
                    #pragma unroll
                    for (int i = 0; i < 16; ++i){ c0[i]=0.f; c1[i]=0.f; c2[i]=0.f; }
                    gemm64(a1h + (size_t)m0 * 1024, a1l + (size_t)m0 * 1024,
                           W2h + (size_t)(cg * 64) * 1024, W2l + (size_t)(cg * 64) * 1024,
                           1024, c0, c1, c2);
                    const int col = cg * 64 + (w & 1) * 32 + (lane & 31);
                    const float bb = b2[col];
                    const int rbase = m0 + (w >> 1) * 32 + 4 * (lane >> 5);
                    #pragma unroll
                    for (int r = 0; r < 16; ++r){
                        int row = rbase + (r & 3) + 8 * (r >> 2);
                        float z = c0[r] + c1[r] + c2[r] + bb;
                        split_store(tanhf(z), a2h, a2l, (size_t)row * 1024 + col);
                    }
                }
                ++epoch; rg_bar(flg, rg, cg, epoch);

                // ---- stage C: k[..][cg*32..+32] = a2 @ W3 + b3, RK update
                {
                    f32x16 c0, c1, c2;
                    #pragma unroll
                    for (int i = 0; i < 16; ++i){ c0[i]=0.f; c1[i]=0.f; c2[i]=0.f; }
                    gemmC(a2h + (size_t)m0 * 1024, a2l + (size_t)m0 * 1024,
                          W3h + (size_t)(cg * 32) * 1024, W3l + (size_t)(cg * 32) * 1024,
                          c0, c1, c2);
                    if (w < 2){
                        const int col = cg * 32 + (lane & 31);
                        const float bb = b3[col];
                        const int rbase = m0 + w * 32 + 4 * (lane >> 5);
                        #pragma unroll
                        for (int r = 0; r < 16; ++r){
                            int row = rbase + (r & 3) + 8 * (r >> 2);
                            size_t idx = (size_t)row * 512 + col;
                            float z = c0[r] + c1[r] + c2[r] + bb;
                            if (s == 0){
                                kacc[idx] = z;
                                split_store(y32[idx] + 0.5f * hs * z, yth, ytl, idx);
                            } else if (s == 3){
                                float yn = y32[idx] + (hs / 6.0f) * (kacc[idx] + z);
                                y32[idx] = yn;
                                split_store(yn, yh, yl, idx);
                            } else {
                                kacc[idx] += 2.0f * z;
                                float hc = (s == 1) ? 0.5f * hs : hs;
                                split_store(y32[idx] + hc * z, yth, ytl, idx);
                            }
                        }
                    }
                }
                ++epoch; rg_bar(flg, rg, cg, epoch);
            }
        }
    }
}

extern "C" void kernel_launch(void* const* d_in, const int* in_sizes, int n_in,
                              void* d_out, int out_size, void* d_ws, size_t ws_size,
                              hipStream_t stream)
{
    (void)in_sizes; (void)n_in; (void)out_size; (void)ws_size;
    const float* x   = (const float*)d_in[0];
    const float* Wi1 = (const float*)d_in[1];
    const float* bi1 = (const float*)d_in[2];
    const float* Wi2 = (const float*)d_in[3];
    const float* bi2 = (const float*)d_in[4];
    const float* Wr  = (const float*)d_in[5];
    const float* br  = (const float*)d_in[6];
    const float* oW1 = (const float*)d_in[7];
    const float* ob1 = (const float*)d_in[8];
    const float* oW2 = (const float*)d_in[9];
    const float* ob2 = (const float*)d_in[10];
    const float* oW3 = (const float*)d_in[11];
    const float* ob3 = (const float*)d_in[12];
    const float* Wo1 = (const float*)d_in[13];
    const float* bo1 = (const float*)d_in[14];
    const float* Wo2 = (const float*)d_in[15];
    const float* bo2 = (const float*)d_in[16];
    float* out = (float*)d_out;

    char* p = (char*)d_ws;
    auto alloc = [&](size_t bytes)->char*{ char* r = p; p += (bytes + 255) & ~(size_t)255; return r; };

    us* xh = (us*)alloc(1024*256*2);  us* xl = (us*)alloc(1024*256*2);
    us* Wi1th = (us*)alloc(512*256*2);  us* Wi1tl = (us*)alloc(512*256*2);
    us* Wi2th = (us*)alloc(512*512*2);  us* Wi2tl = (us*)alloc(512*512*2);
    us* Wrth  = (us*)alloc(512*256*2);  us* Wrtl  = (us*)alloc(512*256*2);
    us* oW1th = (us*)alloc(5ull*1024*512*2);  us* oW1tl = (us*)alloc(5ull*1024*512*2);
    us* oW2th = (us*)alloc(5ull*1024*1024*2); us* oW2tl = (us*)alloc(5ull*1024*1024*2);
    us* oW3th = (us*)alloc(5ull*512*1024*2);  us* oW3tl = (us*)alloc(5ull*512*1024*2);
    us* Wo1th = (us*)alloc(512*512*2);  us* Wo1tl = (us*)alloc(512*512*2);
    us* Wo2th = (us*)alloc(128*512*2);  us* Wo2tl = (us*)alloc(128*512*2);
    us* t1h = (us*)alloc(1024ull*512*2);  us* t1l = (us*)alloc(1024ull*512*2);   // MLP temps
    us* a1h = (us*)alloc(1024ull*1024*2); us* a1l = (us*)alloc(1024ull*1024*2);
    us* a2h = (us*)alloc(1024ull*1024*2); us* a2l = (us*)alloc(1024ull*1024*2);
    us* yh  = (us*)alloc(1024ull*512*2);  us* yl  = (us*)alloc(1024ull*512*2);
    us* yth = (us*)alloc(1024ull*512*2);  us* ytl = (us*)alloc(1024ull*512*2);
    float* y32  = (float*)alloc(1024ull*512*4);
    float* kacc = (float*)alloc(1024ull*512*4);   // also rres in input block
    unsigned* syncz = (unsigned*)alloc((16*16*64 + 16) * 4);  // flags + slot counters
    unsigned* flg = syncz;
    unsigned* slotctr = syncz + 16*16*64;
    float* rres = kacc;  // alias: rres consumed before kacc's first RK write

    const int ZN = 16*16*64 + 16;

    // ---- preprocessing (2 dispatches) ----
    hipLaunchKernelGGL(xsplit, dim3(1024), dim3(256), 0, stream, x, xh, xl, 1024*256, syncz, ZN);

    WsTable T;
    for (int i = 0; i < 22; ++i){
        T.d[i].src = nullptr; T.d[i].h = nullptr; T.d[i].l = nullptr;
        T.d[i].K = 32; T.d[i].N = 32; T.d[i].tile0 = 0x7fffffff;  // sentinel
    }
    int tile_acc = 0, di = 0;
    auto addW = [&](const float* W, us* th, us* tl, int K, int N){
        T.d[di].src = W; T.d[di].h = th; T.d[di].l = tl;
        T.d[di].K = K; T.d[di].N = N; T.d[di].tile0 = tile_acc;
        tile_acc += (K/32) * (N/32); ++di;
    };
    addW(Wi1, Wi1th, Wi1tl, 256, 512);
    addW(Wi2, Wi2th, Wi2tl, 512, 512);
    addW(Wr,  Wrth,  Wrtl,  256, 512);
    for (int L = 0; L < 5; ++L){
        addW(oW1 + (size_t)L*512*1024,  oW1th + (size_t)L*1024*512,  oW1tl + (size_t)L*1024*512,  512, 1024);
        addW(oW2 + (size_t)L*1024*1024, oW2th + (size_t)L*1024*1024, oW2tl + (size_t)L*1024*1024, 1024, 1024);
        addW(oW3 + (size_t)L*1024*512,  oW3th + (size_t)L*512*1024,  oW3tl + (size_t)L*512*1024,  1024, 512);
    }
    addW(Wo1, Wo1th, Wo1tl, 512, 512);
    addW(Wo2, Wo2th, Wo2tl, 512, 128);
    hipLaunchKernelGGL(wsplit_all, dim3(tile_acc), dim3(256), 0, stream, T);

    auto G = [&](const us* ah, const us* al, const us* bh, const us* bl,
                 const float* bias, int N, int K, int mode,
                 us* oh, us* ol, float* of, const float* rs){
        dim3 grid(N/64, BATCH/32);
        hipLaunchKernelGGL(gemm3p, grid, dim3(128), 0, stream,
                           ah, al, bh, bl, bias, BATCH, N, K, mode, oh, ol, of, rs);
    };

    // ---- input block (3 dispatches) ----
    G(xh, xl, Wrth, Wrtl, br, 512, 256, EM_PLAIN_F32, nullptr, nullptr, rres, nullptr);
    G(xh, xl, Wi1th, Wi1tl, bi1, 512, 256, EM_TANH, t1h, t1l, nullptr, nullptr);
    G(t1h, t1l, Wi2th, Wi2tl, bi2, 512, 512, EM_TANH_RES, yh, yl, y32, rres);

    // ---- the entire 5-layer RK4 ODE stack (1 dispatch, XCD-local) ----
    hipLaunchKernelGGL(fused_ode, dim3(256), dim3(256), 0, stream,
                       oW1th, oW1tl, ob1, oW2th, oW2tl, ob2, oW3th, oW3tl, ob3,
                       yh, yl, yth, ytl, a1h, a1l, a2h, a2l, y32, kacc, flg, slotctr);

    // ---- output MLP (2 dispatches) ----
    G(yh, yl, Wo1th, Wo1tl, bo1, 512, 512, EM_TANH, t1h, t1l, nullptr, nullptr);
    G(t1h, t1l, Wo2th, Wo2tl, bo2, 128, 512, EM_TANH_OUT, nullptr, nullptr, out, nullptr);
}